// Round 1
// baseline (4162.209 us; speedup 1.0000x reference)
//
#include <hip/hip_runtime.h>
#include <hip/hip_bf16.h>
#include <math.h>

// Problem constants
#define BB  32
#define CC  256
#define HZd 13
#define HXd 25
#define NZ  169     // 13*13
#define NX  625     // 25*25

__device__ __forceinline__ float geluf(float x) {
  return 0.5f * x * (1.0f + erff(x * 0.7071067811865476f));
}

struct GP {
  const float* A;  const float* B;  const float* B2;  const float* mask;
  const float* bias; const float* gamma; const float* beta; const float* mean; const float* var;
  const float* resid;
  float* out;
  int M, N, K;
  long aB, bB, b2B, outB;   // per-batch element strides (0 for shared weights)
};

#define TM 64
#define TN 64
#define TK 16

// AG: 0 = A[m,k] row-major (ld=K) ; 1 = A[m,k] = Abase[k*M + m] (transposed source)
// BG: 0 = B[k,n] row-major (ld=N) ; 1 = im2col 3x3 pad1 from [C,25,25]
//     2 = im2col 5x5 pad2 from concat(fi_out, xf_g*mask)  ; 3 = B + B2 (same layout)
// EPI:0 = none ; 1 = +bias ; 2 = +bias,BN,GELU ; 3 = +resid (same layout as out)
template<int AG, int BG, int EPI>
__global__ __launch_bounds__(256) void gemm_k(GP p) {
  const int b  = blockIdx.z;
  const int m0 = blockIdx.y * TM;
  const int n0 = blockIdx.x * TN;
  const float* Ab = p.A + (size_t)b * p.aB;
  const float* Bb = p.B + (size_t)b * p.bB;
  __shared__ __align__(16) float As[TK][TM + 4];
  __shared__ __align__(16) float Bs[TK][TN + 4];
  const int tid = threadIdx.x;
  const int tx = tid & 15, ty = tid >> 4;
  float acc[4][4] = {{0.f}};
  const int nK = (p.K + TK - 1) / TK;
  for (int kb = 0; kb < nK; ++kb) {
    const int k0 = kb * TK;
    // ---- stage A tile ----
    if (AG == 0) {
      #pragma unroll
      for (int i = 0; i < 4; ++i) {
        int e = tid * 4 + i;
        int am = e >> 4, ak = e & 15;
        int gm = m0 + am, gk = k0 + ak;
        float v = 0.f;
        if (gm < p.M && gk < p.K) v = Ab[(size_t)gm * p.K + gk];
        As[ak][am] = v;
      }
    } else {
      #pragma unroll
      for (int i = 0; i < 4; ++i) {
        int e = tid + 256 * i;
        int ak = e >> 6, am = e & 63;
        int gm = m0 + am, gk = k0 + ak;
        float v = 0.f;
        if (gm < p.M && gk < p.K) v = Ab[(size_t)gk * p.M + gm];
        As[ak][am] = v;
      }
    }
    // ---- stage B tile ----
    #pragma unroll
    for (int i = 0; i < 4; ++i) {
      int e = tid + 256 * i;
      int bk = e >> 6, bn = e & 63;
      int gk = k0 + bk, gn = n0 + bn;
      float v = 0.f;
      if (gk < p.K && gn < p.N) {
        if (BG == 0) {
          v = Bb[(size_t)gk * p.N + gn];
        } else if (BG == 3) {
          v = Bb[(size_t)gk * p.N + gn]
            + (p.B2 + (size_t)b * p.b2B)[(size_t)gk * p.N + gn];
        } else if (BG == 1) {
          int c = gk / 9, r = gk - c * 9, kh = r / 3, kw = r - kh * 3;
          int py = gn / 25, px = gn - py * 25;
          int iy = py + kh - 1, ix = px + kw - 1;
          if ((unsigned)iy < 25u && (unsigned)ix < 25u)
            v = Bb[(size_t)c * 625 + iy * 25 + ix];
        } else { // BG == 2
          int c = gk / 25, r = gk - c * 25, kh = r / 5, kw = r - kh * 5;
          int py = gn / 25, px = gn - py * 25;
          int iy = py + kh - 2, ix = px + kw - 2;
          if ((unsigned)iy < 25u && (unsigned)ix < 25u) {
            int pp = iy * 25 + ix;
            if (c < 256) v = Bb[(size_t)c * 625 + pp];
            else v = (p.B2 + (size_t)b * p.b2B)[(size_t)(c - 256) * 625 + pp]
                     * p.mask[b * 625 + pp];
          }
        }
      }
      Bs[bk][bn] = v;
    }
    __syncthreads();
    #pragma unroll
    for (int kk = 0; kk < TK; ++kk) {
      float av[4], bv[4];
      #pragma unroll
      for (int i2 = 0; i2 < 4; ++i2) av[i2] = As[kk][ty * 4 + i2];
      #pragma unroll
      for (int j2 = 0; j2 < 4; ++j2) bv[j2] = Bs[kk][tx * 4 + j2];
      #pragma unroll
      for (int i2 = 0; i2 < 4; ++i2)
        #pragma unroll
        for (int j2 = 0; j2 < 4; ++j2)
          acc[i2][j2] = fmaf(av[i2], bv[j2], acc[i2][j2]);
    }
    __syncthreads();
  }
  // ---- epilogue ----
  #pragma unroll
  for (int i = 0; i < 4; ++i) {
    int gm = m0 + ty * 4 + i;
    if (gm >= p.M) continue;
    float bs = 0.f, sBN = 1.f, tBN = 0.f;
    if (EPI == 1 || EPI == 2) bs = p.bias[gm];
    if (EPI == 2) {
      float sc = p.gamma[gm] / sqrtf(p.var[gm] + 1e-5f);
      sBN = sc; tBN = p.beta[gm] - p.mean[gm] * sc;
    }
    #pragma unroll
    for (int j = 0; j < 4; ++j) {
      int gn = n0 + tx * 4 + j;
      if (gn >= p.N) continue;
      float v = acc[i][j];
      if (EPI == 1) v += bs;
      if (EPI == 2) { v += bs; v = v * sBN + tBN; v = geluf(v); }
      if (EPI == 3) v += p.resid[(size_t)b * p.outB + (size_t)gm * p.N + gn];
      p.out[(size_t)b * p.outB + (size_t)gm * p.N + gn] = v;
    }
  }
}

// ---------------- sparsemax (exact, Michelot projection) ----------------
// One block (256 threads) per row; in-place. d <= 768.
__global__ __launch_bounds__(256) void sparsemax_k(float* __restrict__ S, int d) {
  const int row = blockIdx.x;
  float* s = S + (size_t)row * d;
  const int tid = threadIdx.x;
  const int wid = tid >> 6, lane = tid & 63;
  float v[3]; bool act[3];
  #pragma unroll
  for (int j = 0; j < 3; ++j) {
    int idx = tid + j * 256;
    bool ok = idx < d;
    v[j] = ok ? s[idx] : -1e30f;
    act[j] = ok;
  }
  __shared__ float red[16];
  // row max
  float mx = fmaxf(fmaxf(v[0], v[1]), v[2]);
  #pragma unroll
  for (int o = 32; o; o >>= 1) mx = fmaxf(mx, __shfl_down(mx, o));
  if (lane == 0) red[wid] = mx;
  __syncthreads();
  if (tid == 0) red[0] = fmaxf(fmaxf(red[0], red[1]), fmaxf(red[2], red[3]));
  __syncthreads();
  mx = red[0];
  __syncthreads();
  #pragma unroll
  for (int j = 0; j < 3; ++j) if (act[j]) v[j] -= mx;
  float tau = 0.f;
  for (int it = 0; it < 700; ++it) {
    float ls = 0.f, lc = 0.f;
    #pragma unroll
    for (int j = 0; j < 3; ++j) if (act[j]) { ls += v[j]; lc += 1.f; }
    #pragma unroll
    for (int o = 32; o; o >>= 1) { ls += __shfl_down(ls, o); lc += __shfl_down(lc, o); }
    if (lane == 0) { red[wid] = ls; red[4 + wid] = lc; }
    __syncthreads();
    if (tid == 0) {
      float Sm = 0.f, Cn = 0.f;
      #pragma unroll
      for (int w = 0; w < 4; ++w) { Sm += red[w]; Cn += red[4 + w]; }
      red[8] = (Sm - 1.f) / Cn;
      red[9] = 0.f;
    }
    __syncthreads();
    tau = red[8];
    bool ch = false;
    #pragma unroll
    for (int j = 0; j < 3; ++j)
      if (act[j] && v[j] <= tau) { act[j] = false; ch = true; }
    if (ch) red[9] = 1.f;
    __syncthreads();
    if (red[9] == 0.f) break;
  }
  #pragma unroll
  for (int j = 0; j < 3; ++j) {
    int idx = tid + j * 256;
    if (idx < d) s[idx] = fmaxf(v[j] - tau, 0.f);
  }
}

// ------------- mask: any(si2>0) -> largest 8-CC -> fill holes -------------
__global__ __launch_bounds__(640) void cc_kernel(const float* __restrict__ si2,
                                                 float* __restrict__ mask) {
  const int b = blockIdx.x, tid = threadIdx.x;
  __shared__ int lab[625];
  __shared__ int counts[626];
  __shared__ int flag, best;
  const bool in = tid < 625;
  const int y = tid / 25, x = tid - (tid / 25) * 25;
  bool mv = false;
  if (in) {
    const float* base = si2 + (size_t)b * NZ * NX + tid;
    for (int n = 0; n < NZ; ++n) mv = mv || (base[(size_t)n * NX] > 0.f);
    lab[tid] = mv ? tid + 1 : 0;
  }
  __syncthreads();
  // 8-connected label max-propagation to fixpoint
  for (int it = 0; it < 1000; ++it) {
    if (tid == 0) flag = 0;
    __syncthreads();
    int nl = 0;
    if (in && mv) {
      nl = lab[tid];
      #pragma unroll
      for (int dy = -1; dy <= 1; ++dy)
        #pragma unroll
        for (int dx = -1; dx <= 1; ++dx) {
          int yy = y + dy, xx = x + dx;
          if ((unsigned)yy < 25u && (unsigned)xx < 25u) nl = max(nl, lab[yy * 25 + xx]);
        }
    }
    __syncthreads();
    if (in && mv && nl != lab[tid]) { lab[tid] = nl; flag = 1; }
    __syncthreads();
    if (flag == 0) break;
  }
  // histogram + argmax (tie -> smallest index, matching jnp.argmax)
  if (tid < 626) counts[tid] = (tid == 0) ? -1 : 0;
  if (tid == 0) best = (int)0x80000000;
  __syncthreads();
  if (in && mv) atomicAdd(&counts[lab[tid]], 1);
  __syncthreads();
  if (tid < 626) atomicMax(&best, counts[tid] * 1024 + (1023 - tid));
  __syncthreads();
  const int largest = 1023 - (best & 1023);
  const bool comp = in && mv && (lab[tid] == largest);
  const bool bg = in && !comp;
  const bool border = in && (y == 0 || y == 24 || x == 0 || x == 24);
  __syncthreads();
  if (in) lab[tid] = (bg && border) ? 1 : 0;   // reuse lab as reach flags
  __syncthreads();
  // 4-connected flood of background from border
  for (int it = 0; it < 1000; ++it) {
    if (tid == 0) flag = 0;
    __syncthreads();
    int r = 0;
    if (in && bg && !lab[tid]) {
      if (y > 0  && lab[tid - 25]) r = 1;
      if (y < 24 && lab[tid + 25]) r = 1;
      if (x > 0  && lab[tid - 1])  r = 1;
      if (x < 24 && lab[tid + 1])  r = 1;
    }
    __syncthreads();
    if (r) { lab[tid] = 1; flag = 1; }
    __syncthreads();
    if (flag == 0) break;
  }
  if (in) mask[(size_t)b * NX + tid] = lab[tid] ? 0.f : 1.f;
}

extern "C" void kernel_launch(void* const* d_in, const int* in_sizes, int n_in,
                              void* d_out, int out_size, void* d_ws, size_t ws_size,
                              hipStream_t stream) {
  const float* zf     = (const float*)d_in[0];
  const float* xf     = (const float*)d_in[1];
  const float* sup_w  = (const float*)d_in[2];
  const float* sup_b  = (const float*)d_in[3];
  const float* sup_g  = (const float*)d_in[4];
  const float* sup_be = (const float*)d_in[5];
  const float* sup_m  = (const float*)d_in[6];
  const float* sup_v  = (const float*)d_in[7];
  const float* q_w    = (const float*)d_in[8];
  const float* q_b    = (const float*)d_in[9];
  const float* q_g    = (const float*)d_in[10];
  const float* q_be   = (const float*)d_in[11];
  const float* q_m    = (const float*)d_in[12];
  const float* q_v    = (const float*)d_in[13];
  const float* g_w1   = (const float*)d_in[14];
  const float* g_b1   = (const float*)d_in[15];
  const float* g_w2   = (const float*)d_in[16];
  const float* g_b2   = (const float*)d_in[17];
  const float* g_g    = (const float*)d_in[18];
  const float* g_be   = (const float*)d_in[19];
  const float* g_m    = (const float*)d_in[20];
  const float* g_v    = (const float*)d_in[21];
  const float* fi_w   = (const float*)d_in[22];
  const float* fi_b   = (const float*)d_in[23];
  const float* fi_g   = (const float*)d_in[24];
  const float* fi_be  = (const float*)d_in[25];
  const float* fi_m   = (const float*)d_in[26];
  const float* fi_v   = (const float*)d_in[27];
  const float* fi1_w  = (const float*)d_in[28];
  const float* fi1_b  = (const float*)d_in[29];
  const float* fi1_g  = (const float*)d_in[30];
  const float* fi1_be = (const float*)d_in[31];
  const float* fi1_m  = (const float*)d_in[32];
  const float* fi1_v  = (const float*)d_in[33];

  float* ws = (float*)d_ws;
  float* xf_trans = ws;                     // 32*256*625
  float* zf_trans = xf_trans + 5120000;     // 32*256*169
  float* gtmp     = zf_trans + 1384448;     // 32*256*625
  float* xf_g     = gtmp + 5120000;         // 32*256*625
  float* zf_s     = xf_g + 5120000;         // 32*169*169
  float* zp2      = zf_s + 913952;          // 32*256*169
  float* si       = zp2 + 1384448;          // 32*169*625
  float* si2      = si + 3380000;           // 32*169*625
  float* fi_out   = si2 + 3380000;          // 32*256*625
  float* maskb    = fi_out + 5120000;       // 32*625

  dim3 blk(256);
  GP p;

  // 1) xf_trans = gelu(bn_q(q_w @ xf + q_b))
  p = GP{}; p.A = q_w; p.B = xf; p.bias = q_b;
  p.gamma = q_g; p.beta = q_be; p.mean = q_m; p.var = q_v;
  p.out = xf_trans; p.M = CC; p.N = NX; p.K = CC;
  p.aB = 0; p.bB = (long)CC * NX; p.outB = (long)CC * NX;
  gemm_k<0,0,2><<<dim3(10,4,BB), blk, 0, stream>>>(p);

  // 2) zf_trans = gelu(bn_sup(sup_w @ zf + sup_b))
  p = GP{}; p.A = sup_w; p.B = zf; p.bias = sup_b;
  p.gamma = sup_g; p.beta = sup_be; p.mean = sup_m; p.var = sup_v;
  p.out = zf_trans; p.M = CC; p.N = NZ; p.K = CC;
  p.aB = 0; p.bB = (long)CC * NZ; p.outB = (long)CC * NZ;
  gemm_k<0,0,2><<<dim3(3,4,BB), blk, 0, stream>>>(p);

  // 3) gtmp = conv3x3(xf, g_w1) + g_b1
  p = GP{}; p.A = g_w1; p.B = xf; p.bias = g_b1;
  p.out = gtmp; p.M = CC; p.N = NX; p.K = CC * 9;
  p.aB = 0; p.bB = (long)CC * NX; p.outB = (long)CC * NX;
  gemm_k<0,1,1><<<dim3(10,4,BB), blk, 0, stream>>>(p);

  // 4) xf_g = gelu(bn_g(g_w2 @ gtmp + g_b2))
  p = GP{}; p.A = g_w2; p.B = gtmp; p.bias = g_b2;
  p.gamma = g_g; p.beta = g_be; p.mean = g_m; p.var = g_v;
  p.out = xf_g; p.M = CC; p.N = NX; p.K = CC;
  p.aB = 0; p.bB = (long)CC * NX; p.outB = (long)CC * NX;
  gemm_k<0,0,2><<<dim3(10,4,BB), blk, 0, stream>>>(p);

  // 5) zf_s_logits[n,m] = sum_c zf_trans[c,n] * zf_trans[c,m]
  p = GP{}; p.A = zf_trans; p.B = zf_trans;
  p.out = zf_s; p.M = NZ; p.N = NZ; p.K = CC;
  p.aB = (long)CC * NZ; p.bB = (long)CC * NZ; p.outB = (long)NZ * NZ;
  gemm_k<1,0,0><<<dim3(3,3,BB), blk, 0, stream>>>(p);

  // 6) zf_s = sparsemax(zf_s_logits) rows of length 169
  sparsemax_k<<<BB * NZ, blk, 0, stream>>>(zf_s, NZ);

  // 7) zp2[c,m] = zf[c,m] + sum_n zf[c,n] * zf_s[n,m]
  p = GP{}; p.A = zf; p.B = zf_s; p.resid = zf;
  p.out = zp2; p.M = CC; p.N = NZ; p.K = NZ;
  p.aB = (long)CC * NZ; p.bB = (long)NZ * NZ; p.outB = (long)CC * NZ;
  gemm_k<0,0,3><<<dim3(3,4,BB), blk, 0, stream>>>(p);

  // 8) si_logits[n,m] = sum_c zp2[c,n] * xf[c,m]
  p = GP{}; p.A = zp2; p.B = xf;
  p.out = si; p.M = NZ; p.N = NX; p.K = CC;
  p.aB = (long)CC * NZ; p.bB = (long)CC * NX; p.outB = (long)NZ * NX;
  gemm_k<1,0,0><<<dim3(10,3,BB), blk, 0, stream>>>(p);

  // 9) si2_logits[n,m] = sum_c zp2[c,n] * xf_trans[c,m]
  p = GP{}; p.A = zp2; p.B = xf_trans;
  p.out = si2; p.M = NZ; p.N = NX; p.K = CC;
  p.aB = (long)CC * NZ; p.bB = (long)CC * NX; p.outB = (long)NZ * NX;
  gemm_k<1,0,0><<<dim3(10,3,BB), blk, 0, stream>>>(p);

  // 10) sparsemax rows of length 625
  sparsemax_k<<<BB * NZ, blk, 0, stream>>>(si, NX);
  sparsemax_k<<<BB * NZ, blk, 0, stream>>>(si2, NX);

  // 11) mask from si2 (any over n, largest CC, fill holes)
  cc_kernel<<<BB, dim3(640), 0, stream>>>(si2, maskb);

  // 12) fi_out = gelu(bn_fi(fi_w @ (si + si2) + fi_b))
  p = GP{}; p.A = fi_w; p.B = si; p.B2 = si2; p.bias = fi_b;
  p.gamma = fi_g; p.beta = fi_be; p.mean = fi_m; p.var = fi_v;
  p.out = fi_out; p.M = CC; p.N = NX; p.K = NZ;
  p.aB = 0; p.bB = (long)NZ * NX; p.b2B = (long)NZ * NX; p.outB = (long)CC * NX;
  gemm_k<0,3,2><<<dim3(10,4,BB), blk, 0, stream>>>(p);

  // 13) out = gelu(bn_fi1(conv5x5(concat(fi_out, xf_g*mask), fi1_w) + fi1_b))
  p = GP{}; p.A = fi1_w; p.B = fi_out; p.B2 = xf_g; p.mask = maskb; p.bias = fi1_b;
  p.gamma = fi1_g; p.beta = fi1_be; p.mean = fi1_m; p.var = fi1_v;
  p.out = (float*)d_out; p.M = CC; p.N = NX; p.K = 512 * 25;
  p.aB = 0; p.bB = (long)CC * NX; p.b2B = (long)CC * NX; p.outB = (long)CC * NX;
  gemm_k<0,2,2><<<dim3(10,4,BB), blk, 0, stream>>>(p);
}

// Round 2
// 2229.224 us; speedup vs baseline: 1.8671x; 1.8671x over previous
//
#include <hip/hip_runtime.h>
#include <hip/hip_bf16.h>
#include <math.h>

// Problem constants
#define BB  32
#define CC  256
#define HZd 13
#define HXd 25
#define NZ  169     // 13*13
#define NX  625     // 25*25

typedef _Float16 f16x4 __attribute__((ext_vector_type(4)));
typedef _Float16 f16x8 __attribute__((ext_vector_type(8)));
typedef float    f32x4 __attribute__((ext_vector_type(4)));

__device__ __forceinline__ float geluf(float x) {
  return 0.5f * x * (1.0f + erff(x * 0.7071067811865476f));
}

// ======================= fp32 vector GEMM (mask-path ops) =======================
struct GP {
  const float* A;  const float* B;  const float* B2;  const float* mask;
  const float* bias; const float* gamma; const float* beta; const float* mean; const float* var;
  const float* resid;
  float* out;
  int M, N, K;
  long aB, bB, b2B, outB;
};

#define TM 64
#define TN 64
#define TK 16

// AG: 0 = A[m,k] row-major ; 1 = A[m,k] = Abase[k*M + m]
// EPI:0 = none ; 2 = +bias,BN,GELU ; 3 = +resid
template<int AG, int EPI>
__global__ __launch_bounds__(256) void gemm_k(GP p) {
  const int b  = blockIdx.z;
  const int m0 = blockIdx.y * TM;
  const int n0 = blockIdx.x * TN;
  const float* Ab = p.A + (size_t)b * p.aB;
  const float* Bb = p.B + (size_t)b * p.bB;
  __shared__ __align__(16) float As[TK][TM + 4];
  __shared__ __align__(16) float Bs[TK][TN + 4];
  const int tid = threadIdx.x;
  const int tx = tid & 15, ty = tid >> 4;
  float acc[4][4] = {{0.f}};
  const int nK = (p.K + TK - 1) / TK;
  for (int kb = 0; kb < nK; ++kb) {
    const int k0 = kb * TK;
    if (AG == 0) {
      #pragma unroll
      for (int i = 0; i < 4; ++i) {
        int e = tid * 4 + i;
        int am = e >> 4, ak = e & 15;
        int gm = m0 + am, gk = k0 + ak;
        float v = 0.f;
        if (gm < p.M && gk < p.K) v = Ab[(size_t)gm * p.K + gk];
        As[ak][am] = v;
      }
    } else {
      #pragma unroll
      for (int i = 0; i < 4; ++i) {
        int e = tid + 256 * i;
        int ak = e >> 6, am = e & 63;
        int gm = m0 + am, gk = k0 + ak;
        float v = 0.f;
        if (gm < p.M && gk < p.K) v = Ab[(size_t)gk * p.M + gm];
        As[ak][am] = v;
      }
    }
    #pragma unroll
    for (int i = 0; i < 4; ++i) {
      int e = tid + 256 * i;
      int bk = e >> 6, bn = e & 63;
      int gk = k0 + bk, gn = n0 + bn;
      float v = 0.f;
      if (gk < p.K && gn < p.N) v = Bb[(size_t)gk * p.N + gn];
      Bs[bk][bn] = v;
    }
    __syncthreads();
    #pragma unroll
    for (int kk = 0; kk < TK; ++kk) {
      float av[4], bv[4];
      #pragma unroll
      for (int i2 = 0; i2 < 4; ++i2) av[i2] = As[kk][ty * 4 + i2];
      #pragma unroll
      for (int j2 = 0; j2 < 4; ++j2) bv[j2] = Bs[kk][tx * 4 + j2];
      #pragma unroll
      for (int i2 = 0; i2 < 4; ++i2)
        #pragma unroll
        for (int j2 = 0; j2 < 4; ++j2)
          acc[i2][j2] = fmaf(av[i2], bv[j2], acc[i2][j2]);
    }
    __syncthreads();
  }
  #pragma unroll
  for (int i = 0; i < 4; ++i) {
    int gm = m0 + ty * 4 + i;
    if (gm >= p.M) continue;
    float bs = 0.f, sBN = 1.f, tBN = 0.f;
    if (EPI == 2) {
      bs = p.bias[gm];
      float sc = p.gamma[gm] / sqrtf(p.var[gm] + 1e-5f);
      sBN = sc; tBN = p.beta[gm] - p.mean[gm] * sc;
    }
    #pragma unroll
    for (int j = 0; j < 4; ++j) {
      int gn = n0 + tx * 4 + j;
      if (gn >= p.N) continue;
      float v = acc[i][j];
      if (EPI == 2) { v += bs; v = v * sBN + tBN; v = geluf(v); }
      if (EPI == 3) v += p.resid[(size_t)b * p.outB + (size_t)gm * p.N + gn];
      p.out[(size_t)b * p.outB + (size_t)gm * p.N + gn] = v;
    }
  }
}

// ======================= weight pre-transpose to f16 =======================
// W [M][C2][R] fp32  ->  Wt [R][M][C2p] f16 (zero-padded c >= C2)
__global__ __launch_bounds__(256) void wtr_k(const float* __restrict__ W,
                                             _Float16* __restrict__ Wt,
                                             int M, int C2, int C2p, int R) {
  size_t o = (size_t)blockIdx.x * 256 + threadIdx.x;
  size_t total = (size_t)R * M * C2p;
  if (o >= total) return;
  int c = (int)(o % C2p);
  int t = (int)(o / C2p);
  int m = t % M;
  int r = t / M;
  float v = 0.f;
  if (c < C2) v = W[((size_t)m * C2 + c) * R + r];
  Wt[o] = (_Float16)v;
}

// ======================= f16 MFMA conv-as-GEMM =======================
// out[b][m][n] = epi( sum_{r,c} Wt[r][m][c] * Bsrc[b][c][pix(n)+off(r)] )
// Tap-decomposed conv: R taps of Rw x Rw kernel (pad = Rw/2), C2 channels.
struct MP {
  const _Float16* Wt;       // [R][256][C2p]
  const float* B0; const float* B1; const float* mask;
  const float* bias; const float* gamma; const float* beta; const float* mean; const float* var;
  float* out;               // [b][256][625]
  int R, Rw, C2, C2p;
  long b0B, b1B;
};

// BGM: 0 = B0 only ; 1 = concat(B0, B1*mask) (C2=512) ; 2 = B0 + B1
// EPI: 1 = +bias ; 2 = +bias,BN,GELU
template<int BGM, int EPI>
__global__ __launch_bounds__(256) void mgemm_k(MP p) {
  const int b  = blockIdx.z;
  const int m0 = blockIdx.y * 128;
  const int n0 = blockIdx.x * 64;
  __shared__ __align__(16) _Float16 As[128][40];
  __shared__ __align__(16) _Float16 Bs[64][40];
  const int tid = threadIdx.x;
  const int w = tid >> 6, lane = tid & 63;
  const int lm = lane & 15, lk = (lane >> 4) * 4;
  // A staging coords
  const int am = tid >> 1;
  const int ac = (tid & 1) * 16;
  // B staging coords: one pixel per thread, 8 channels
  const int bn = tid >> 2;           // 0..63
  const int kb = (tid & 3) * 8;      // 0,8,16,24
  const int ng = n0 + bn;
  const bool nv = ng < NX;
  const int py = ng / 25, px = ng - (ng / 25) * 25;
  const float* B0b = p.B0 + (size_t)b * p.b0B;
  const float* B1b = (BGM != 0) ? (p.B1 + (size_t)b * p.b1B) : nullptr;
  const float* mb  = (BGM == 1) ? (p.mask + (size_t)b * NX) : nullptr;
  const int pad = p.Rw >> 1;

  f32x4 acc[2][4] = {};

  for (int r = 0; r < p.R; ++r) {
    const int kh = r / p.Rw, kw = r - (r / p.Rw) * p.Rw;
    const int dy = kh - pad, dx = kw - pad;
    const int iy = py + dy, ix = px + dx;
    const bool pv = nv && ((unsigned)iy < 25u) && ((unsigned)ix < 25u);
    const int pp = iy * 25 + ix;
    const _Float16* Wr = p.Wt + ((size_t)r * 256 + m0) * p.C2p;
    for (int c0 = 0; c0 < p.C2p; c0 += 32) {
      // ---- stage A (f16, vectorized) ----
      {
        const _Float16* src = &Wr[(size_t)am * p.C2p + c0 + ac];
        f16x8 a0 = *(const f16x8*)(src);
        f16x8 a1 = *(const f16x8*)(src + 8);
        *(f16x8*)&As[am][ac]     = a0;
        *(f16x8*)&As[am][ac + 8] = a1;
      }
      // ---- stage B (gather fp32 -> f16, one b128 write) ----
      {
        f16x8 bv;
        #pragma unroll
        for (int i = 0; i < 8; ++i) {
          int cc = c0 + kb + i;
          float v = 0.f;
          if (pv && cc < p.C2) {
            if (BGM == 0) v = B0b[(size_t)cc * NX + pp];
            else if (BGM == 1)
              v = (cc < 256) ? B0b[(size_t)cc * NX + pp]
                             : B1b[(size_t)(cc - 256) * NX + pp] * mb[pp];
            else v = B0b[(size_t)cc * NX + pp] + B1b[(size_t)cc * NX + pp];
          }
          bv[i] = (_Float16)v;
        }
        *(f16x8*)&Bs[bn][kb] = bv;
      }
      __syncthreads();
      // ---- MFMA: wave w computes rows [w*32, w*32+32) x cols [0,64) ----
      #pragma unroll
      for (int ks = 0; ks < 2; ++ks) {
        f16x4 af[2], bf[4];
        #pragma unroll
        for (int fm = 0; fm < 2; ++fm)
          af[fm] = *(const f16x4*)&As[w * 32 + fm * 16 + lm][ks * 16 + lk];
        #pragma unroll
        for (int fn = 0; fn < 4; ++fn)
          bf[fn] = *(const f16x4*)&Bs[fn * 16 + lm][ks * 16 + lk];
        #pragma unroll
        for (int fm = 0; fm < 2; ++fm)
          #pragma unroll
          for (int fn = 0; fn < 4; ++fn)
            acc[fm][fn] = __builtin_amdgcn_mfma_f32_16x16x16f16(
                af[fm], bf[fn], acc[fm][fn], 0, 0, 0);
      }
      __syncthreads();
    }
  }
  // ---- epilogue ----
  #pragma unroll
  for (int fm = 0; fm < 2; ++fm) {
    const int rbase = m0 + w * 32 + fm * 16 + (lane >> 4) * 4;
    #pragma unroll
    for (int rr = 0; rr < 4; ++rr) {
      const int row = rbase + rr;
      float bs = p.bias[row];
      float sBN = 1.f, tBN = 0.f;
      if (EPI == 2) {
        float sc = p.gamma[row] / sqrtf(p.var[row] + 1e-5f);
        sBN = sc; tBN = p.beta[row] - p.mean[row] * sc;
      }
      #pragma unroll
      for (int fn = 0; fn < 4; ++fn) {
        const int col = n0 + fn * 16 + lm;
        if (col < NX) {
          float v = acc[fm][fn][rr] + bs;
          if (EPI == 2) v = geluf(v * sBN + tBN);
          p.out[(size_t)b * (256 * NX) + (size_t)row * NX + col] = v;
        }
      }
    }
  }
}

// ---------------- sparsemax (exact, Michelot projection) ----------------
__global__ __launch_bounds__(256) void sparsemax_k(float* __restrict__ S, int d) {
  const int row = blockIdx.x;
  float* s = S + (size_t)row * d;
  const int tid = threadIdx.x;
  const int wid = tid >> 6, lane = tid & 63;
  float v[3]; bool act[3];
  #pragma unroll
  for (int j = 0; j < 3; ++j) {
    int idx = tid + j * 256;
    bool ok = idx < d;
    v[j] = ok ? s[idx] : -1e30f;
    act[j] = ok;
  }
  __shared__ float red[16];
  float mx = fmaxf(fmaxf(v[0], v[1]), v[2]);
  #pragma unroll
  for (int o = 32; o; o >>= 1) mx = fmaxf(mx, __shfl_down(mx, o));
  if (lane == 0) red[wid] = mx;
  __syncthreads();
  if (tid == 0) red[0] = fmaxf(fmaxf(red[0], red[1]), fmaxf(red[2], red[3]));
  __syncthreads();
  mx = red[0];
  __syncthreads();
  #pragma unroll
  for (int j = 0; j < 3; ++j) if (act[j]) v[j] -= mx;
  float tau = 0.f;
  for (int it = 0; it < 700; ++it) {
    float ls = 0.f, lc = 0.f;
    #pragma unroll
    for (int j = 0; j < 3; ++j) if (act[j]) { ls += v[j]; lc += 1.f; }
    #pragma unroll
    for (int o = 32; o; o >>= 1) { ls += __shfl_down(ls, o); lc += __shfl_down(lc, o); }
    if (lane == 0) { red[wid] = ls; red[4 + wid] = lc; }
    __syncthreads();
    if (tid == 0) {
      float Sm = 0.f, Cn = 0.f;
      #pragma unroll
      for (int w2 = 0; w2 < 4; ++w2) { Sm += red[w2]; Cn += red[4 + w2]; }
      red[8] = (Sm - 1.f) / Cn;
      red[9] = 0.f;
    }
    __syncthreads();
    tau = red[8];
    bool ch = false;
    #pragma unroll
    for (int j = 0; j < 3; ++j)
      if (act[j] && v[j] <= tau) { act[j] = false; ch = true; }
    if (ch) red[9] = 1.f;
    __syncthreads();
    if (red[9] == 0.f) break;
  }
  #pragma unroll
  for (int j = 0; j < 3; ++j) {
    int idx = tid + j * 256;
    if (idx < d) s[idx] = fmaxf(v[j] - tau, 0.f);
  }
}

// ------------- mask: any(si2>0) -> largest 8-CC -> fill holes -------------
__global__ __launch_bounds__(640) void cc_kernel(const float* __restrict__ si2,
                                                 float* __restrict__ mask) {
  const int b = blockIdx.x, tid = threadIdx.x;
  __shared__ int lab[625];
  __shared__ int counts[626];
  __shared__ int flag, best;
  const bool in = tid < 625;
  const int y = tid / 25, x = tid - (tid / 25) * 25;
  bool mv = false;
  if (in) {
    const float* base = si2 + (size_t)b * NZ * NX + tid;
    for (int n = 0; n < NZ; ++n) mv = mv || (base[(size_t)n * NX] > 0.f);
    lab[tid] = mv ? tid + 1 : 0;
  }
  __syncthreads();
  for (int it = 0; it < 1000; ++it) {
    if (tid == 0) flag = 0;
    __syncthreads();
    int nl = 0;
    if (in && mv) {
      nl = lab[tid];
      #pragma unroll
      for (int dy = -1; dy <= 1; ++dy)
        #pragma unroll
        for (int dx = -1; dx <= 1; ++dx) {
          int yy = y + dy, xx = x + dx;
          if ((unsigned)yy < 25u && (unsigned)xx < 25u) nl = max(nl, lab[yy * 25 + xx]);
        }
    }
    __syncthreads();
    if (in && mv && nl != lab[tid]) { lab[tid] = nl; flag = 1; }
    __syncthreads();
    if (flag == 0) break;
  }
  if (tid < 626) counts[tid] = (tid == 0) ? -1 : 0;
  if (tid == 0) best = (int)0x80000000;
  __syncthreads();
  if (in && mv) atomicAdd(&counts[lab[tid]], 1);
  __syncthreads();
  if (tid < 626) atomicMax(&best, counts[tid] * 1024 + (1023 - tid));
  __syncthreads();
  const int largest = 1023 - (best & 1023);
  const bool comp = in && mv && (lab[tid] == largest);
  const bool bg = in && !comp;
  const bool border = in && (y == 0 || y == 24 || x == 0 || x == 24);
  __syncthreads();
  if (in) lab[tid] = (bg && border) ? 1 : 0;
  __syncthreads();
  for (int it = 0; it < 1000; ++it) {
    if (tid == 0) flag = 0;
    __syncthreads();
    int r = 0;
    if (in && bg && !lab[tid]) {
      if (y > 0  && lab[tid - 25]) r = 1;
      if (y < 24 && lab[tid + 25]) r = 1;
      if (x > 0  && lab[tid - 1])  r = 1;
      if (x < 24 && lab[tid + 1])  r = 1;
    }
    __syncthreads();
    if (r) { lab[tid] = 1; flag = 1; }
    __syncthreads();
    if (flag == 0) break;
  }
  if (in) mask[(size_t)b * NX + tid] = lab[tid] ? 0.f : 1.f;
}

extern "C" void kernel_launch(void* const* d_in, const int* in_sizes, int n_in,
                              void* d_out, int out_size, void* d_ws, size_t ws_size,
                              hipStream_t stream) {
  const float* zf     = (const float*)d_in[0];
  const float* xf     = (const float*)d_in[1];
  const float* sup_w  = (const float*)d_in[2];
  const float* sup_b  = (const float*)d_in[3];
  const float* sup_g  = (const float*)d_in[4];
  const float* sup_be = (const float*)d_in[5];
  const float* sup_m  = (const float*)d_in[6];
  const float* sup_v  = (const float*)d_in[7];
  const float* q_w    = (const float*)d_in[8];
  const float* q_b    = (const float*)d_in[9];
  const float* q_g    = (const float*)d_in[10];
  const float* q_be   = (const float*)d_in[11];
  const float* q_m    = (const float*)d_in[12];
  const float* q_v    = (const float*)d_in[13];
  const float* g_w1   = (const float*)d_in[14];
  const float* g_b1   = (const float*)d_in[15];
  const float* g_w2   = (const float*)d_in[16];
  const float* g_b2   = (const float*)d_in[17];
  const float* g_g    = (const float*)d_in[18];
  const float* g_be   = (const float*)d_in[19];
  const float* g_m    = (const float*)d_in[20];
  const float* g_v    = (const float*)d_in[21];
  const float* fi_w   = (const float*)d_in[22];
  const float* fi_b   = (const float*)d_in[23];
  const float* fi_g   = (const float*)d_in[24];
  const float* fi_be  = (const float*)d_in[25];
  const float* fi_m   = (const float*)d_in[26];
  const float* fi_v   = (const float*)d_in[27];
  const float* fi1_w  = (const float*)d_in[28];
  const float* fi1_b  = (const float*)d_in[29];
  const float* fi1_g  = (const float*)d_in[30];
  const float* fi1_be = (const float*)d_in[31];
  const float* fi1_m  = (const float*)d_in[32];
  const float* fi1_v  = (const float*)d_in[33];

  float* ws = (float*)d_ws;
  float* xf_trans = ws;                     // 32*256*625 = 5,120,000
  float* zf_trans = xf_trans + 5120000;     // 32*256*169 = 1,384,448
  float* gtmp     = zf_trans + 1384448;     // 32*256*625
  float* xf_g     = gtmp + 5120000;         // 32*256*625
  float* zf_s     = xf_g + 5120000;         // 32*169*169
  float* zp2      = zf_s + 913952;          // 32*256*169
  float* si       = zp2 + 1384448;          // 32*169*625
  float* si2      = si + 3380000;           // 32*169*625
  float* fi_out   = si2 + 3380000;          // 32*256*625
  float* maskb    = fi_out + 5120000;       // 32*625

  // f16 weight buffers reuse the xf_trans region (dead after step 9)
  _Float16* wt_g1  = (_Float16*)xf_trans;   // 9*256*256   = 589,824
  _Float16* wt_g2  = wt_g1 + 589824;        // 1*256*256   = 65,536
  _Float16* wt_fi  = wt_g2 + 65536;         // 1*256*192   = 49,152
  _Float16* wt_fi1 = wt_fi + 49152;         // 25*256*512  = 3,276,800

  dim3 blk(256);
  GP p;

  // ---- mask-decision chain (exact fp32) ----
  // 1) xf_trans = gelu(bn_q(q_w @ xf + q_b))
  p = GP{}; p.A = q_w; p.B = xf; p.bias = q_b;
  p.gamma = q_g; p.beta = q_be; p.mean = q_m; p.var = q_v;
  p.out = xf_trans; p.M = CC; p.N = NX; p.K = CC;
  p.aB = 0; p.bB = (long)CC * NX; p.outB = (long)CC * NX;
  gemm_k<0,2><<<dim3(10,4,BB), blk, 0, stream>>>(p);

  // 2) zf_trans = gelu(bn_sup(sup_w @ zf + sup_b))
  p = GP{}; p.A = sup_w; p.B = zf; p.bias = sup_b;
  p.gamma = sup_g; p.beta = sup_be; p.mean = sup_m; p.var = sup_v;
  p.out = zf_trans; p.M = CC; p.N = NZ; p.K = CC;
  p.aB = 0; p.bB = (long)CC * NZ; p.outB = (long)CC * NZ;
  gemm_k<0,2><<<dim3(3,4,BB), blk, 0, stream>>>(p);

  // 5) zf_s_logits[n,m] = sum_c zf_trans[c,n] * zf_trans[c,m]
  p = GP{}; p.A = zf_trans; p.B = zf_trans;
  p.out = zf_s; p.M = NZ; p.N = NZ; p.K = CC;
  p.aB = (long)CC * NZ; p.bB = (long)CC * NZ; p.outB = (long)NZ * NZ;
  gemm_k<1,0><<<dim3(3,3,BB), blk, 0, stream>>>(p);

  // 6) zf_s = sparsemax(zf_s_logits)
  sparsemax_k<<<BB * NZ, blk, 0, stream>>>(zf_s, NZ);

  // 7) zp2[c,m] = zf[c,m] + sum_n zf[c,n] * zf_s[n,m]
  p = GP{}; p.A = zf; p.B = zf_s; p.resid = zf;
  p.out = zp2; p.M = CC; p.N = NZ; p.K = NZ;
  p.aB = (long)CC * NZ; p.bB = (long)NZ * NZ; p.outB = (long)CC * NZ;
  gemm_k<0,3><<<dim3(3,4,BB), blk, 0, stream>>>(p);

  // 8) si_logits[n,m] = sum_c zp2[c,n] * xf[c,m]
  p = GP{}; p.A = zp2; p.B = xf;
  p.out = si; p.M = NZ; p.N = NX; p.K = CC;
  p.aB = (long)CC * NZ; p.bB = (long)CC * NX; p.outB = (long)NZ * NX;
  gemm_k<1,0><<<dim3(10,3,BB), blk, 0, stream>>>(p);

  // 9) si2_logits[n,m] = sum_c zp2[c,n] * xf_trans[c,m]
  p = GP{}; p.A = zp2; p.B = xf_trans;
  p.out = si2; p.M = NZ; p.N = NX; p.K = CC;
  p.aB = (long)CC * NZ; p.bB = (long)CC * NX; p.outB = (long)NZ * NX;
  gemm_k<1,0><<<dim3(10,3,BB), blk, 0, stream>>>(p);

  // 10) sparsemax rows of length 625
  sparsemax_k<<<BB * NZ, blk, 0, stream>>>(si, NX);
  sparsemax_k<<<BB * NZ, blk, 0, stream>>>(si2, NX);

  // 11) mask from si2
  cc_kernel<<<BB, dim3(640), 0, stream>>>(si2, maskb);

  // ---- xf_trans now dead: build f16 weights in its space ----
  wtr_k<<<(9*256*256 + 255)/256,  blk, 0, stream>>>(g_w1,  wt_g1,  256, 256, 256, 9);
  wtr_k<<<(256*256   + 255)/256,  blk, 0, stream>>>(g_w2,  wt_g2,  256, 256, 256, 1);
  wtr_k<<<(256*192   + 255)/256,  blk, 0, stream>>>(fi_w,  wt_fi,  256, 169, 192, 1);
  wtr_k<<<(25*256*512+ 255)/256,  blk, 0, stream>>>(fi1_w, wt_fi1, 256, 512, 512, 25);

  // ---- output path on MFMA (f16 in, fp32 accum) ----
  MP mp;

  // 3) gtmp = conv3x3(xf, g_w1) + g_b1
  mp = MP{}; mp.Wt = wt_g1; mp.B0 = xf; mp.bias = g_b1;
  mp.out = gtmp; mp.R = 9; mp.Rw = 3; mp.C2 = 256; mp.C2p = 256;
  mp.b0B = (long)CC * NX;
  mgemm_k<0,1><<<dim3(10,2,BB), blk, 0, stream>>>(mp);

  // 4) xf_g = gelu(bn_g(g_w2 @ gtmp + g_b2))
  mp = MP{}; mp.Wt = wt_g2; mp.B0 = gtmp; mp.bias = g_b2;
  mp.gamma = g_g; mp.beta = g_be; mp.mean = g_m; mp.var = g_v;
  mp.out = xf_g; mp.R = 1; mp.Rw = 1; mp.C2 = 256; mp.C2p = 256;
  mp.b0B = (long)CC * NX;
  mgemm_k<0,2><<<dim3(10,2,BB), blk, 0, stream>>>(mp);

  // 12) fi_out = gelu(bn_fi(fi_w @ (si + si2) + fi_b))
  mp = MP{}; mp.Wt = wt_fi; mp.B0 = si; mp.B1 = si2; mp.bias = fi_b;
  mp.gamma = fi_g; mp.beta = fi_be; mp.mean = fi_m; mp.var = fi_v;
  mp.out = fi_out; mp.R = 1; mp.Rw = 1; mp.C2 = 169; mp.C2p = 192;
  mp.b0B = (long)NZ * NX; mp.b1B = (long)NZ * NX;
  mgemm_k<2,2><<<dim3(10,2,BB), blk, 0, stream>>>(mp);

  // 13) out = gelu(bn_fi1(conv5x5(concat(fi_out, xf_g*mask), fi1_w) + fi1_b))
  mp = MP{}; mp.Wt = wt_fi1; mp.B0 = fi_out; mp.B1 = xf_g; mp.mask = maskb;
  mp.bias = fi1_b; mp.gamma = fi1_g; mp.beta = fi1_be; mp.mean = fi1_m; mp.var = fi1_v;
  mp.out = (float*)d_out; mp.R = 25; mp.Rw = 5; mp.C2 = 512; mp.C2p = 512;
  mp.b0B = (long)CC * NX; mp.b1B = (long)CC * NX;
  mgemm_k<1,2><<<dim3(10,2,BB), blk, 0, stream>>>(mp);
}

// Round 6
// 1032.094 us; speedup vs baseline: 4.0328x; 2.1599x over previous
//
#include <hip/hip_runtime.h>
#include <hip/hip_bf16.h>
#include <math.h>

// Problem constants
#define BB  32
#define CC  256
#define NZ  169     // 13*13
#define NX  625     // 25*25

typedef _Float16 f16x4 __attribute__((ext_vector_type(4)));
typedef _Float16 f16x8 __attribute__((ext_vector_type(8)));
typedef float    f32x4 __attribute__((ext_vector_type(4)));

__device__ __forceinline__ float geluf(float x) {
  return 0.5f * x * (1.0f + erff(x * 0.7071067811865476f));
}

// ======================= fp32 vector GEMM (mask-path ops) =======================
struct GP {
  const float* A;  const float* B;
  const float* bias; const float* gamma; const float* beta; const float* mean; const float* var;
  const float* resid;
  float* out;
  int M, N, K;
  long aB, bB, outB;
};

#define TM 64
#define TN 64
#define TK 16

// AG: 0 = A[m,k] row-major ; 1 = A[m,k] = Abase[k*M + m]
// EPI:0 = none ; 2 = +bias,BN,GELU ; 3 = +resid
template<int AG, int EPI>
__global__ __launch_bounds__(256) void gemm_k(GP p) {
  const int b  = blockIdx.z;
  const int m0 = blockIdx.y * TM;
  const int n0 = blockIdx.x * TN;
  const float* Ab = p.A + (size_t)b * p.aB;
  const float* Bb = p.B + (size_t)b * p.bB;
  __shared__ __align__(16) float As[TK][TM + 4];
  __shared__ __align__(16) float Bs[TK][TN + 4];
  const int tid = threadIdx.x;
  const int tx = tid & 15, ty = tid >> 4;
  float acc[4][4] = {{0.f}};
  const int nK = (p.K + TK - 1) / TK;
  for (int kb = 0; kb < nK; ++kb) {
    const int k0 = kb * TK;
    if (AG == 0) {
      #pragma unroll
      for (int i = 0; i < 4; ++i) {
        int e = tid * 4 + i;
        int am = e >> 4, ak = e & 15;
        int gm = m0 + am, gk = k0 + ak;
        float v = 0.f;
        if (gm < p.M && gk < p.K) v = Ab[(size_t)gm * p.K + gk];
        As[ak][am] = v;
      }
    } else {
      #pragma unroll
      for (int i = 0; i < 4; ++i) {
        int e = tid + 256 * i;
        int ak = e >> 6, am = e & 63;
        int gm = m0 + am, gk = k0 + ak;
        float v = 0.f;
        if (gm < p.M && gk < p.K) v = Ab[(size_t)gk * p.M + gm];
        As[ak][am] = v;
      }
    }
    #pragma unroll
    for (int i = 0; i < 4; ++i) {
      int e = tid + 256 * i;
      int bk = e >> 6, bn = e & 63;
      int gk = k0 + bk, gn = n0 + bn;
      float v = 0.f;
      if (gk < p.K && gn < p.N) v = Bb[(size_t)gk * p.N + gn];
      Bs[bk][bn] = v;
    }
    __syncthreads();
    #pragma unroll
    for (int kk = 0; kk < TK; ++kk) {
      float av[4], bv[4];
      #pragma unroll
      for (int i2 = 0; i2 < 4; ++i2) av[i2] = As[kk][ty * 4 + i2];
      #pragma unroll
      for (int j2 = 0; j2 < 4; ++j2) bv[j2] = Bs[kk][tx * 4 + j2];
      #pragma unroll
      for (int i2 = 0; i2 < 4; ++i2)
        #pragma unroll
        for (int j2 = 0; j2 < 4; ++j2)
          acc[i2][j2] = fmaf(av[i2], bv[j2], acc[i2][j2]);
    }
    __syncthreads();
  }
  #pragma unroll
  for (int i = 0; i < 4; ++i) {
    int gm = m0 + ty * 4 + i;
    if (gm >= p.M) continue;
    float bs = 0.f, sBN = 1.f, tBN = 0.f;
    if (EPI == 2) {
      bs = p.bias[gm];
      float sc = p.gamma[gm] / sqrtf(p.var[gm] + 1e-5f);
      sBN = sc; tBN = p.beta[gm] - p.mean[gm] * sc;
    }
    #pragma unroll
    for (int j = 0; j < 4; ++j) {
      int gn = n0 + tx * 4 + j;
      if (gn >= p.N) continue;
      float v = acc[i][j];
      if (EPI == 2) { v += bs; v = v * sBN + tBN; v = geluf(v); }
      if (EPI == 3) v += p.resid[(size_t)b * p.outB + (size_t)gm * p.N + gn];
      p.out[(size_t)b * p.outB + (size_t)gm * p.N + gn] = v;
    }
  }
}

// ======================= weight pre-transpose to f16 =======================
// W [M][C2][R] fp32  ->  Wt [R][M][C2p] f16 (zero-padded c >= C2)
__global__ __launch_bounds__(256) void wtr_k(const float* __restrict__ W,
                                             _Float16* __restrict__ Wt,
                                             int M, int C2, int C2p, int R) {
  size_t o = (size_t)blockIdx.x * 256 + threadIdx.x;
  size_t total = (size_t)R * M * C2p;
  if (o >= total) return;
  int c = (int)(o % C2p);
  int t = (int)(o / C2p);
  int m = t % M;
  int r = t / M;
  float v = 0.f;
  if (c < C2) v = W[((size_t)m * C2 + c) * R + r];
  Wt[o] = (_Float16)v;
}

// ======================= NCHW f32 (+opt add) -> NHWC f16 =======================
// in [b][C][625] (+in2) -> out [b][625][Cp], zero-pad c>=C
__global__ __launch_bounds__(256) void cvt_k(const float* __restrict__ A,
                                             const float* __restrict__ A2,
                                             _Float16* __restrict__ O,
                                             int C, int Cp, long total) {
  long o = (long)blockIdx.x * 256 + threadIdx.x;
  if (o >= total) return;
  int c = (int)(o % Cp);
  long t = o / Cp;
  int pp = (int)(t % NX);
  int b = (int)(t / NX);
  float v = 0.f;
  if (c < C) {
    size_t src = ((size_t)b * C + c) * NX + pp;
    v = A[src];
    if (A2) v += A2[src];
  }
  O[o] = (_Float16)v;
}

// ======================= f16 MFMA conv-as-GEMM (NHWC acts) =======================
// out[b][m][n] = epi( sum_{r,c} Wt[r][m][c] * U[b][pix(n,r)][c] )
struct MP {
  const _Float16* Wt;       // [R][256][C2p]
  const _Float16* U;        // [b][625][C2p]
  const float* mask;        // [b][625] (MASKED: applies to c>=256)
  const float* bias; const float* gamma; const float* beta; const float* mean; const float* var;
  float* out;               // f32 NCHW [b][256][625]   (OUT16 == 0)
  _Float16* out16;          // f16 NHWC [b][625][oC2p]  (OUT16 == 1)
  int R, Rw, C2p;
  long uB;                  // per-batch U stride
  int oC2p, oCoff;
};

// EPI: 1 = +bias ; 2 = +bias,BN,GELU
template<int EPI, int OUT16, int MASKED>
__global__ __launch_bounds__(256) void mgemm_k(MP p) {
  const int b  = blockIdx.z;
  const int m0 = blockIdx.y * 128;
  const int n0 = blockIdx.x * 64;
  __shared__ __align__(16) _Float16 As[128][72];
  __shared__ __align__(16) _Float16 Bs[64][72];
  const int tid = threadIdx.x;
  const int w = tid >> 6, lane = tid & 63;
  const int lm = lane & 15, lk = (lane >> 4) * 4;
  const int am = tid >> 1, aco = (tid & 1) * 32;   // A stage: row, col-offset
  const int bn = tid >> 2, bc = (tid & 3) * 16;    // B stage: pixel, chan-offset
  const int ng = n0 + bn;
  const bool nv = ng < NX;
  const int py = ng / 25, px = ng - (ng / 25) * 25;
  const _Float16* Ub = p.U + (size_t)b * p.uB;
  const float* mb = MASKED ? (p.mask + (size_t)b * NX) : nullptr;
  const int pad = p.Rw >> 1;

  f32x4 acc[2][4] = {};

  for (int r = 0; r < p.R; ++r) {
    const int kh = r / p.Rw, kw = r - (r / p.Rw) * p.Rw;
    const int iy = py + kh - pad, ix = px + kw - pad;
    const bool pv = nv && ((unsigned)iy < 25u) && ((unsigned)ix < 25u);
    const int pp = iy * 25 + ix;
    const _Float16* Up = pv ? (Ub + (size_t)pp * p.C2p) : nullptr;
    _Float16 mh = (_Float16)1.f;
    if (MASKED && pv) mh = (_Float16)mb[pp];
    const _Float16* Wr = p.Wt + ((size_t)r * 256 + m0) * p.C2p;
    for (int c0 = 0; c0 < p.C2p; c0 += 64) {
      // ---- A: 128x64 f16, 32 per thread, coalesced ----
      const _Float16* Arow = Wr + (size_t)am * p.C2p + c0 + aco;
      f16x8 a0 = *(const f16x8*)(Arow);
      f16x8 a1 = *(const f16x8*)(Arow + 8);
      f16x8 a2 = *(const f16x8*)(Arow + 16);
      f16x8 a3 = *(const f16x8*)(Arow + 24);
      // ---- B: 64x64 f16, 16 per thread, coalesced ----
      f16x8 v0 = {}, v1 = {};
      if (pv) {
        const _Float16* Bp = Up + c0 + bc;
        v0 = *(const f16x8*)(Bp);
        v1 = *(const f16x8*)(Bp + 8);
        if (MASKED && (c0 + bc) >= 256) { v0 = v0 * mh; v1 = v1 * mh; }
      }
      *(f16x8*)&As[am][aco]      = a0;
      *(f16x8*)&As[am][aco + 8]  = a1;
      *(f16x8*)&As[am][aco + 16] = a2;
      *(f16x8*)&As[am][aco + 24] = a3;
      *(f16x8*)&Bs[bn][bc]     = v0;
      *(f16x8*)&Bs[bn][bc + 8] = v1;
      __syncthreads();
      #pragma unroll
      for (int ks = 0; ks < 4; ++ks) {
        f16x4 af[2], bf[4];
        #pragma unroll
        for (int fm = 0; fm < 2; ++fm)
          af[fm] = *(const f16x4*)&As[w * 32 + fm * 16 + lm][ks * 16 + lk];
        #pragma unroll
        for (int fn = 0; fn < 4; ++fn)
          bf[fn] = *(const f16x4*)&Bs[fn * 16 + lm][ks * 16 + lk];
        #pragma unroll
        for (int fm = 0; fm < 2; ++fm)
          #pragma unroll
          for (int fn = 0; fn < 4; ++fn)
            acc[fm][fn] = __builtin_amdgcn_mfma_f32_16x16x16f16(
                af[fm], bf[fn], acc[fm][fn], 0, 0, 0);
      }
      __syncthreads();
    }
  }
  // ---- epilogue ----
  #pragma unroll
  for (int fm = 0; fm < 2; ++fm) {
    const int rbase = m0 + w * 32 + fm * 16 + (lane >> 4) * 4;
    #pragma unroll
    for (int rr = 0; rr < 4; ++rr) {
      const int row = rbase + rr;
      float bs = p.bias[row];
      float sBN = 1.f, tBN = 0.f;
      if (EPI == 2) {
        float sc = p.gamma[row] / sqrtf(p.var[row] + 1e-5f);
        sBN = sc; tBN = p.beta[row] - p.mean[row] * sc;
      }
      #pragma unroll
      for (int fn = 0; fn < 4; ++fn) {
        const int col = n0 + fn * 16 + lm;
        if (col < NX) {
          float v = acc[fm][fn][rr] + bs;
          if (EPI == 2) v = geluf(v * sBN + tBN);
          if (OUT16) {
            p.out16[((size_t)b * NX + col) * p.oC2p + p.oCoff + row] = (_Float16)v;
          } else {
            p.out[(size_t)b * (256 * NX) + (size_t)row * NX + col] = v;
          }
        }
      }
    }
  }
}

// ---------------- sparsemax (exact, Michelot projection) ----------------
__global__ __launch_bounds__(256) void sparsemax_k(float* __restrict__ S, int d) {
  const int row = blockIdx.x;
  float* s = S + (size_t)row * d;
  const int tid = threadIdx.x;
  const int wid = tid >> 6, lane = tid & 63;
  float v[3]; bool act[3];
  #pragma unroll
  for (int j = 0; j < 3; ++j) {
    int idx = tid + j * 256;
    bool ok = idx < d;
    v[j] = ok ? s[idx] : -1e30f;
    act[j] = ok;
  }
  __shared__ float red[16];
  float mx = fmaxf(fmaxf(v[0], v[1]), v[2]);
  #pragma unroll
  for (int o = 32; o; o >>= 1) mx = fmaxf(mx, __shfl_down(mx, o));
  if (lane == 0) red[wid] = mx;
  __syncthreads();
  if (tid == 0) red[0] = fmaxf(fmaxf(red[0], red[1]), fmaxf(red[2], red[3]));
  __syncthreads();
  mx = red[0];
  __syncthreads();
  #pragma unroll
  for (int j = 0; j < 3; ++j) if (act[j]) v[j] -= mx;
  float tau = 0.f;
  for (int it = 0; it < 700; ++it) {
    float ls = 0.f, lc = 0.f;
    #pragma unroll
    for (int j = 0; j < 3; ++j) if (act[j]) { ls += v[j]; lc += 1.f; }
    #pragma unroll
    for (int o = 32; o; o >>= 1) { ls += __shfl_down(ls, o); lc += __shfl_down(lc, o); }
    if (lane == 0) { red[wid] = ls; red[4 + wid] = lc; }
    __syncthreads();
    if (tid == 0) {
      float Sm = 0.f, Cn = 0.f;
      #pragma unroll
      for (int w2 = 0; w2 < 4; ++w2) { Sm += red[w2]; Cn += red[4 + w2]; }
      red[8] = (Sm - 1.f) / Cn;
      red[9] = 0.f;
    }
    __syncthreads();
    tau = red[8];
    bool ch = false;
    #pragma unroll
    for (int j = 0; j < 3; ++j)
      if (act[j] && v[j] <= tau) { act[j] = false; ch = true; }
    if (ch) red[9] = 1.f;
    __syncthreads();
    if (red[9] == 0.f) break;
  }
  #pragma unroll
  for (int j = 0; j < 3; ++j) {
    int idx = tid + j * 256;
    if (idx < d) s[idx] = fmaxf(v[j] - tau, 0.f);
  }
}

// ------------- mask: any(si2>0) -> largest 8-CC -> fill holes -------------
__global__ __launch_bounds__(640) void cc_kernel(const float* __restrict__ si2,
                                                 float* __restrict__ mask) {
  const int b = blockIdx.x, tid = threadIdx.x;
  __shared__ int lab[625];
  __shared__ int counts[626];
  __shared__ int flag, best;
  const bool in = tid < 625;
  const int y = tid / 25, x = tid - (tid / 25) * 25;
  bool mv = false;
  if (in) {
    const float* base = si2 + (size_t)b * NZ * NX + tid;
    for (int n = 0; n < NZ; ++n) mv = mv || (base[(size_t)n * NX] > 0.f);
    lab[tid] = mv ? tid + 1 : 0;
  }
  __syncthreads();
  for (int it = 0; it < 1000; ++it) {
    if (tid == 0) flag = 0;
    __syncthreads();
    int nl = 0;
    if (in && mv) {
      nl = lab[tid];
      #pragma unroll
      for (int dy = -1; dy <= 1; ++dy)
        #pragma unroll
        for (int dx = -1; dx <= 1; ++dx) {
          int yy = y + dy, xx = x + dx;
          if ((unsigned)yy < 25u && (unsigned)xx < 25u) nl = max(nl, lab[yy * 25 + xx]);
        }
    }
    __syncthreads();
    if (in && mv && nl != lab[tid]) { lab[tid] = nl; flag = 1; }
    __syncthreads();
    if (flag == 0) break;
  }
  if (tid < 626) counts[tid] = (tid == 0) ? -1 : 0;
  if (tid == 0) best = (int)0x80000000;
  __syncthreads();
  if (in && mv) atomicAdd(&counts[lab[tid]], 1);
  __syncthreads();
  if (tid < 626) atomicMax(&best, counts[tid] * 1024 + (1023 - tid));
  __syncthreads();
  const int largest = 1023 - (best & 1023);
  const bool comp = in && mv && (lab[tid] == largest);
  const bool bg = in && !comp;
  const bool border = in && (y == 0 || y == 24 || x == 0 || x == 24);
  __syncthreads();
  if (in) lab[tid] = (bg && border) ? 1 : 0;
  __syncthreads();
  for (int it = 0; it < 1000; ++it) {
    if (tid == 0) flag = 0;
    __syncthreads();
    int r = 0;
    if (in && bg && !lab[tid]) {
      if (y > 0  && lab[tid - 25]) r = 1;
      if (y < 24 && lab[tid + 25]) r = 1;
      if (x > 0  && lab[tid - 1])  r = 1;
      if (x < 24 && lab[tid + 1])  r = 1;
    }
    __syncthreads();
    if (r) { lab[tid] = 1; flag = 1; }
    __syncthreads();
    if (flag == 0) break;
  }
  if (in) mask[(size_t)b * NX + tid] = lab[tid] ? 0.f : 1.f;
}

extern "C" void kernel_launch(void* const* d_in, const int* in_sizes, int n_in,
                              void* d_out, int out_size, void* d_ws, size_t ws_size,
                              hipStream_t stream) {
  const float* zf     = (const float*)d_in[0];
  const float* xf     = (const float*)d_in[1];
  const float* sup_w  = (const float*)d_in[2];
  const float* sup_b  = (const float*)d_in[3];
  const float* sup_g  = (const float*)d_in[4];
  const float* sup_be = (const float*)d_in[5];
  const float* sup_m  = (const float*)d_in[6];
  const float* sup_v  = (const float*)d_in[7];
  const float* q_w    = (const float*)d_in[8];
  const float* q_b    = (const float*)d_in[9];
  const float* q_g    = (const float*)d_in[10];
  const float* q_be   = (const float*)d_in[11];
  const float* q_m    = (const float*)d_in[12];
  const float* q_v    = (const float*)d_in[13];
  const float* g_w1   = (const float*)d_in[14];
  const float* g_b1   = (const float*)d_in[15];
  const float* g_w2   = (const float*)d_in[16];
  const float* g_b2   = (const float*)d_in[17];
  const float* g_g    = (const float*)d_in[18];
  const float* g_be   = (const float*)d_in[19];
  const float* g_m    = (const float*)d_in[20];
  const float* g_v    = (const float*)d_in[21];
  const float* fi_w   = (const float*)d_in[22];
  const float* fi_b   = (const float*)d_in[23];
  const float* fi_g   = (const float*)d_in[24];
  const float* fi_be  = (const float*)d_in[25];
  const float* fi_m   = (const float*)d_in[26];
  const float* fi_v   = (const float*)d_in[27];
  const float* fi1_w  = (const float*)d_in[28];
  const float* fi1_b  = (const float*)d_in[29];
  const float* fi1_g  = (const float*)d_in[30];
  const float* fi1_be = (const float*)d_in[31];
  const float* fi1_m  = (const float*)d_in[32];
  const float* fi1_v  = (const float*)d_in[33];

  float* ws = (float*)d_ws;
  float* xf_trans = ws;                     // 5,120,000 (dead after step 9 -> reused for f16 weights)
  float* zf_trans = xf_trans + 5120000;     // 1,384,448
  float* zf_s     = zf_trans + 1384448;     // 913,952
  float* zp2      = zf_s + 913952;          // 1,384,448
  float* si       = zp2 + 1384448;          // 3,380,000
  float* si2      = si + 3380000;           // 3,380,000
  float* maskb    = si2 + 3380000;          // 20,000
  float* tail     = maskb + 20000;

  // f16 activation buffers (fresh space)
  _Float16* xf16 = (_Float16*)tail;         // 32*625*256 = 5,120,000 f16
  _Float16* gt16 = xf16 + 5120000;          // 32*625*256
  _Float16* Ucat = gt16 + 5120000;          // 32*625*512 = 10,240,000
  _Float16* S16  = Ucat + 10240000;         // 32*625*192 = 3,840,000

  // f16 weight buffers overlay the (dead) xf_trans region
  _Float16* wt_g1  = (_Float16*)xf_trans;   // 9*256*256   = 589,824
  _Float16* wt_g2  = wt_g1 + 589824;        // 1*256*256   = 65,536
  _Float16* wt_fi  = wt_g2 + 65536;         // 1*256*192   = 49,152
  _Float16* wt_fi1 = wt_fi + 49152;         // 25*256*512  = 3,276,800  (total 1.99M f32 < 5.12M)

  dim3 blk(256);
  GP p;

  // ---- mask-decision chain (exact fp32) ----
  // 1) xf_trans = gelu(bn_q(q_w @ xf + q_b))
  p = GP{}; p.A = q_w; p.B = xf; p.bias = q_b;
  p.gamma = q_g; p.beta = q_be; p.mean = q_m; p.var = q_v;
  p.out = xf_trans; p.M = CC; p.N = NX; p.K = CC;
  p.aB = 0; p.bB = (long)CC * NX; p.outB = (long)CC * NX;
  gemm_k<0,2><<<dim3(10,4,BB), blk, 0, stream>>>(p);

  // 2) zf_trans = gelu(bn_sup(sup_w @ zf + sup_b))
  p = GP{}; p.A = sup_w; p.B = zf; p.bias = sup_b;
  p.gamma = sup_g; p.beta = sup_be; p.mean = sup_m; p.var = sup_v;
  p.out = zf_trans; p.M = CC; p.N = NZ; p.K = CC;
  p.aB = 0; p.bB = (long)CC * NZ; p.outB = (long)CC * NZ;
  gemm_k<0,2><<<dim3(3,4,BB), blk, 0, stream>>>(p);

  // 5) zf_s_logits[n,m] = sum_c zf_trans[c,n] * zf_trans[c,m]
  p = GP{}; p.A = zf_trans; p.B = zf_trans;
  p.out = zf_s; p.M = NZ; p.N = NZ; p.K = CC;
  p.aB = (long)CC * NZ; p.bB = (long)CC * NZ; p.outB = (long)NZ * NZ;
  gemm_k<1,0><<<dim3(3,3,BB), blk, 0, stream>>>(p);

  // 6) zf_s = sparsemax(zf_s_logits)
  sparsemax_k<<<BB * NZ, blk, 0, stream>>>(zf_s, NZ);

  // 7) zp2[c,m] = zf[c,m] + sum_n zf[c,n] * zf_s[n,m]
  p = GP{}; p.A = zf; p.B = zf_s; p.resid = zf;
  p.out = zp2; p.M = CC; p.N = NZ; p.K = NZ;
  p.aB = (long)CC * NZ; p.bB = (long)NZ * NZ; p.outB = (long)CC * NZ;
  gemm_k<0,3><<<dim3(3,4,BB), blk, 0, stream>>>(p);

  // 8) si_logits[n,m] = sum_c zp2[c,n] * xf[c,m]
  p = GP{}; p.A = zp2; p.B = xf;
  p.out = si; p.M = NZ; p.N = NX; p.K = CC;
  p.aB = (long)CC * NZ; p.bB = (long)CC * NX; p.outB = (long)NZ * NX;
  gemm_k<1,0><<<dim3(10,3,BB), blk, 0, stream>>>(p);

  // 9) si2_logits[n,m] = sum_c zp2[c,n] * xf_trans[c,m]
  p = GP{}; p.A = zp2; p.B = xf_trans;
  p.out = si2; p.M = NZ; p.N = NX; p.K = CC;
  p.aB = (long)CC * NZ; p.bB = (long)CC * NX; p.outB = (long)NZ * NX;
  gemm_k<1,0><<<dim3(10,3,BB), blk, 0, stream>>>(p);

  // 10) sparsemax rows of length 625
  sparsemax_k<<<BB * NZ, blk, 0, stream>>>(si, NX);
  sparsemax_k<<<BB * NZ, blk, 0, stream>>>(si2, NX);

  // 11) mask from si2
  cc_kernel<<<BB, dim3(640), 0, stream>>>(si2, maskb);

  // ---- xf_trans now dead: build f16 weights in its space ----
  wtr_k<<<(9*256*256 + 255)/256,  blk, 0, stream>>>(g_w1,  wt_g1,  256, 256, 256, 9);
  wtr_k<<<(256*256   + 255)/256,  blk, 0, stream>>>(g_w2,  wt_g2,  256, 256, 256, 1);
  wtr_k<<<(256*192   + 255)/256,  blk, 0, stream>>>(fi_w,  wt_fi,  256, 169, 192, 1);
  wtr_k<<<(25*256*512+ 255)/256,  blk, 0, stream>>>(fi1_w, wt_fi1, 256, 512, 512, 25);

  // ---- activation conversions to f16 NHWC ----
  // xf -> xf16 [b][625][256]
  cvt_k<<<(long)(BB*NX*256 + 255)/256, blk, 0, stream>>>(xf, nullptr, xf16, 256, 256, (long)BB*NX*256);
  // si+si2 -> S16 [b][625][192]
  cvt_k<<<(long)(BB*NX*192 + 255)/256, blk, 0, stream>>>(si, si2, S16, 169, 192, (long)BB*NX*192);

  // ---- output path on MFMA (f16 in, fp32 accum), NHWC B operands ----
  MP mp;

  // 3) gt16 = conv3x3(xf, g_w1) + g_b1   (f16 NHWC out)
  mp = MP{}; mp.Wt = wt_g1; mp.U = xf16; mp.bias = g_b1;
  mp.out16 = gt16; mp.R = 9; mp.Rw = 3; mp.C2p = 256;
  mp.uB = (long)NX * 256; mp.oC2p = 256; mp.oCoff = 0;
  mgemm_k<1,1,0><<<dim3(10,2,BB), blk, 0, stream>>>(mp);

  // 4) Ucat[:,256:512] = gelu(bn_g(g_w2 @ gt16 + g_b2))
  mp = MP{}; mp.Wt = wt_g2; mp.U = gt16; mp.bias = g_b2;
  mp.gamma = g_g; mp.beta = g_be; mp.mean = g_m; mp.var = g_v;
  mp.out16 = Ucat; mp.R = 1; mp.Rw = 1; mp.C2p = 256;
  mp.uB = (long)NX * 256; mp.oC2p = 512; mp.oCoff = 256;
  mgemm_k<2,1,0><<<dim3(10,2,BB), blk, 0, stream>>>(mp);

  // 12) Ucat[:,0:256] = gelu(bn_fi(fi_w @ (si + si2) + fi_b))
  mp = MP{}; mp.Wt = wt_fi; mp.U = S16; mp.bias = fi_b;
  mp.gamma = fi_g; mp.beta = fi_be; mp.mean = fi_m; mp.var = fi_v;
  mp.out16 = Ucat; mp.R = 1; mp.Rw = 1; mp.C2p = 192;
  mp.uB = (long)NX * 192; mp.oC2p = 512; mp.oCoff = 0;
  mgemm_k<2,1,0><<<dim3(10,2,BB), blk, 0, stream>>>(mp);

  // 13) out = gelu(bn_fi1(conv5x5(Ucat with mask on c>=256, fi1_w) + fi1_b))
  mp = MP{}; mp.Wt = wt_fi1; mp.U = Ucat; mp.mask = maskb;
  mp.bias = fi1_b; mp.gamma = fi1_g; mp.beta = fi1_be; mp.mean = fi1_m; mp.var = fi1_v;
  mp.out = (float*)d_out; mp.R = 25; mp.Rw = 5; mp.C2p = 512;
  mp.uB = (long)NX * 512;
  mgemm_k<2,0,1><<<dim3(10,2,BB), blk, 0, stream>>>(mp);
}

// Round 8
// 888.956 us; speedup vs baseline: 4.6821x; 1.1610x over previous
//
#include <hip/hip_runtime.h>
#include <hip/hip_bf16.h>
#include <math.h>

// Problem constants
#define BB  32
#define CC  256
#define NZ  169     // 13*13
#define NX  625     // 25*25

typedef _Float16 f16x4 __attribute__((ext_vector_type(4)));
typedef _Float16 f16x8 __attribute__((ext_vector_type(8)));
typedef float    f32x4 __attribute__((ext_vector_type(4)));

__device__ __forceinline__ float geluf(float x) {
  return 0.5f * x * (1.0f + erff(x * 0.7071067811865476f));
}

// ======================= fp32 vector GEMM (mask-path ops) =======================
struct GP {
  const float* A;  const float* B;
  const float* bias; const float* gamma; const float* beta; const float* mean; const float* var;
  const float* resid;
  float* out;
  int M, N, K;
  long aB, bB, outB;
};

#define TM 64
#define TN 64
#define TK 16

// AG: 0 = A[m,k] row-major ; 1 = A[m,k] = Abase[k*M + m]
// EPI:0 = none ; 2 = +bias,BN,GELU ; 3 = +resid
template<int AG, int EPI>
__global__ __launch_bounds__(256) void gemm_k(GP p) {
  const int b  = blockIdx.z;
  const int m0 = blockIdx.y * TM;
  const int n0 = blockIdx.x * TN;
  const float* Ab = p.A + (size_t)b * p.aB;
  const float* Bb = p.B + (size_t)b * p.bB;
  __shared__ __align__(16) float As[TK][TM + 4];
  __shared__ __align__(16) float Bs[TK][TN + 4];
  const int tid = threadIdx.x;
  const int tx = tid & 15, ty = tid >> 4;
  float acc[4][4] = {{0.f}};
  const int nK = (p.K + TK - 1) / TK;
  for (int kb = 0; kb < nK; ++kb) {
    const int k0 = kb * TK;
    if (AG == 0) {
      #pragma unroll
      for (int i = 0; i < 4; ++i) {
        int e = tid * 4 + i;
        int am = e >> 4, ak = e & 15;
        int gm = m0 + am, gk = k0 + ak;
        float v = 0.f;
        if (gm < p.M && gk < p.K) v = Ab[(size_t)gm * p.K + gk];
        As[ak][am] = v;
      }
    } else {
      #pragma unroll
      for (int i = 0; i < 4; ++i) {
        int e = tid + 256 * i;
        int ak = e >> 6, am = e & 63;
        int gm = m0 + am, gk = k0 + ak;
        float v = 0.f;
        if (gm < p.M && gk < p.K) v = Ab[(size_t)gk * p.M + gm];
        As[ak][am] = v;
      }
    }
    #pragma unroll
    for (int i = 0; i < 4; ++i) {
      int e = tid + 256 * i;
      int bk = e >> 6, bn = e & 63;
      int gk = k0 + bk, gn = n0 + bn;
      float v = 0.f;
      if (gk < p.K && gn < p.N) v = Bb[(size_t)gk * p.N + gn];
      Bs[bk][bn] = v;
    }
    __syncthreads();
    #pragma unroll
    for (int kk = 0; kk < TK; ++kk) {
      float av[4], bv[4];
      #pragma unroll
      for (int i2 = 0; i2 < 4; ++i2) av[i2] = As[kk][ty * 4 + i2];
      #pragma unroll
      for (int j2 = 0; j2 < 4; ++j2) bv[j2] = Bs[kk][tx * 4 + j2];
      #pragma unroll
      for (int i2 = 0; i2 < 4; ++i2)
        #pragma unroll
        for (int j2 = 0; j2 < 4; ++j2)
          acc[i2][j2] = fmaf(av[i2], bv[j2], acc[i2][j2]);
    }
    __syncthreads();
  }
  #pragma unroll
  for (int i = 0; i < 4; ++i) {
    int gm = m0 + ty * 4 + i;
    if (gm >= p.M) continue;
    float bs = 0.f, sBN = 1.f, tBN = 0.f;
    if (EPI == 2) {
      bs = p.bias[gm];
      float sc = p.gamma[gm] / sqrtf(p.var[gm] + 1e-5f);
      sBN = sc; tBN = p.beta[gm] - p.mean[gm] * sc;
    }
    #pragma unroll
    for (int j = 0; j < 4; ++j) {
      int gn = n0 + tx * 4 + j;
      if (gn >= p.N) continue;
      float v = acc[i][j];
      if (EPI == 2) { v += bs; v = v * sBN + tBN; v = geluf(v); }
      if (EPI == 3) v += p.resid[(size_t)b * p.outB + (size_t)gm * p.N + gn];
      p.out[(size_t)b * p.outB + (size_t)gm * p.N + gn] = v;
    }
  }
}

// ======================= weight pre-transpose to f16 =======================
// W [M][C2][R] fp32  ->  Wt [R][M][C2p] f16 (zero-padded c >= C2)
__global__ __launch_bounds__(256) void wtr_k(const float* __restrict__ W,
                                             _Float16* __restrict__ Wt,
                                             int M, int C2, int C2p, int R) {
  size_t o = (size_t)blockIdx.x * 256 + threadIdx.x;
  size_t total = (size_t)R * M * C2p;
  if (o >= total) return;
  int c = (int)(o % C2p);
  int t = (int)(o / C2p);
  int m = t % M;
  int r = t / M;
  float v = 0.f;
  if (c < C2) v = W[((size_t)m * C2 + c) * R + r];
  Wt[o] = (_Float16)v;
}

// ======================= NCHW f32 (+opt add) -> NHWC f16 =======================
__global__ __launch_bounds__(256) void cvt_k(const float* __restrict__ A,
                                             const float* __restrict__ A2,
                                             _Float16* __restrict__ O,
                                             int C, int Cp, long total) {
  long o = (long)blockIdx.x * 256 + threadIdx.x;
  if (o >= total) return;
  int c = (int)(o % Cp);
  long t = o / Cp;
  int pp = (int)(t % NX);
  int b = (int)(t / NX);
  float v = 0.f;
  if (c < C) {
    size_t src = ((size_t)b * C + c) * NX + pp;
    v = A[src];
    if (A2) v += A2[src];
  }
  O[o] = (_Float16)v;
}

// ======================= f16 MFMA conv-as-GEMM (NHWC acts) =======================
// out[b][m][n] = epi( sum_{r,c} Wt[r][m][c] * U[b][pix(n,r)][c] )
// 16x16x32 MFMA, LDS stride 64 f16 + 16B-slot XOR swizzle, XCD-aware block swizzle.
struct MP {
  const _Float16* Wt;       // [R][256][C2p]
  const _Float16* U;        // [b][625][C2p]
  const float* mask;        // [b][625] (MASKED: applies to c>=256)
  const float* bias; const float* gamma; const float* beta; const float* mean; const float* var;
  float* out;               // f32 NCHW [b][256][625]   (OUT16 == 0)
  _Float16* out16;          // f16 NHWC [b][625][oC2p]  (OUT16 == 1)
  int R, Rw, C2p;
  long uB;                  // per-batch U stride
  int oC2p, oCoff;
};

// EPI: 1 = +bias ; 2 = +bias,BN,GELU
// Grid MUST be dim3(10,2,32): 640 blocks = 8 XCDs x 80.
template<int EPI, int OUT16, int MASKED>
__global__ __launch_bounds__(256) void mgemm_k(MP p) {
  // ---- XCD-aware bijective swizzle: XCD x handles batches 4x..4x+3 ----
  const int L   = blockIdx.x + 10 * (blockIdx.y + 2 * blockIdx.z); // 0..639
  const int xcd = L & 7;
  const int j   = L >> 3;                 // 0..79
  const int jb  = j / 20;                 // 0..3
  const int b   = (xcd << 2) + jb;
  const int t   = j - jb * 20;            // 0..19
  const int ty2 = t / 10;
  const int m0  = ty2 * 128;
  const int n0  = (t - ty2 * 10) * 64;

  __shared__ __align__(16) _Float16 As[128][64];   // 128B rows, swizzled 16B slots
  __shared__ __align__(16) _Float16 Bs[64][64];
  const int tid = threadIdx.x;
  const int w = tid >> 6, lane = tid & 63;
  const int lm = lane & 15, q = lane >> 4;          // q = k-group 0..3
  const int am = tid >> 1, ah = tid & 1;            // A stage: row, col-half
  const int bn = tid >> 2, bs4 = (tid & 3);         // B stage: pixel, 16-chan chunk
  const int bc = bs4 * 16;
  const int ng = n0 + bn;
  const bool nv = ng < NX;
  const int py = ng / 25, px = ng - (ng / 25) * 25;
  const _Float16* Ub = p.U + (size_t)b * p.uB;
  const float* mb = MASKED ? (p.mask + (size_t)b * NX) : nullptr;
  const int pad = p.Rw >> 1;

  f32x4 acc[2][4] = {};

  for (int r = 0; r < p.R; ++r) {
    const int kh = r / p.Rw, kw = r - (r / p.Rw) * p.Rw;
    const int iy = py + kh - pad, ix = px + kw - pad;
    const bool pv = nv && ((unsigned)iy < 25u) && ((unsigned)ix < 25u);
    const int pp = iy * 25 + ix;
    const _Float16* Up = pv ? (Ub + (size_t)pp * p.C2p) : nullptr;
    _Float16 mh = (_Float16)1.f;
    if (MASKED && pv) mh = (_Float16)mb[pp];
    const _Float16* Wr = p.Wt + ((size_t)r * 256 + m0) * p.C2p;
    for (int c0 = 0; c0 < p.C2p; c0 += 64) {
      // ---- A: 128x64 f16, 32 per thread (4 slots), swizzled writes ----
      const _Float16* Arow = Wr + (size_t)am * p.C2p + c0 + ah * 32;
      f16x8 a0 = *(const f16x8*)(Arow);
      f16x8 a1 = *(const f16x8*)(Arow + 8);
      f16x8 a2 = *(const f16x8*)(Arow + 16);
      f16x8 a3 = *(const f16x8*)(Arow + 24);
      // ---- B: 64x64 f16, 16 per thread (2 slots), swizzled writes ----
      f16x8 v0 = {}, v1 = {};
      if (pv) {
        const _Float16* Bp = Up + c0 + bc;
        v0 = *(const f16x8*)(Bp);
        v1 = *(const f16x8*)(Bp + 8);
        if (MASKED && (c0 + bc) >= 256) { v0 = v0 * mh; v1 = v1 * mh; }
      }
      {
        const int ar7 = am & 7, abase = ah * 4;
        *(f16x8*)&As[am][((abase + 0) ^ ar7) << 3] = a0;
        *(f16x8*)&As[am][((abase + 1) ^ ar7) << 3] = a1;
        *(f16x8*)&As[am][((abase + 2) ^ ar7) << 3] = a2;
        *(f16x8*)&As[am][((abase + 3) ^ ar7) << 3] = a3;
        const int br7 = bn & 7, bbase = bs4 * 2;
        *(f16x8*)&Bs[bn][((bbase + 0) ^ br7) << 3] = v0;
        *(f16x8*)&Bs[bn][((bbase + 1) ^ br7) << 3] = v1;
      }
      __syncthreads();
      // ---- MFMA 16x16x32: wave w -> rows [w*32, w*32+32) x cols [0,64) ----
      #pragma unroll
      for (int ks = 0; ks < 2; ++ks) {
        const int so = (((ks << 2) + q) ^ (lm & 7)) << 3;  // fragment rows ≡ lm (mod 8)
        f16x8 af[2], bf[4];
        #pragma unroll
        for (int fm = 0; fm < 2; ++fm)
          af[fm] = *(const f16x8*)&As[w * 32 + fm * 16 + lm][so];
        #pragma unroll
        for (int fn = 0; fn < 4; ++fn)
          bf[fn] = *(const f16x8*)&Bs[fn * 16 + lm][so];
        #pragma unroll
        for (int fm = 0; fm < 2; ++fm)
          #pragma unroll
          for (int fn = 0; fn < 4; ++fn)
            acc[fm][fn] = __builtin_amdgcn_mfma_f32_16x16x32_f16(
                af[fm], bf[fn], acc[fm][fn], 0, 0, 0);
      }
      __syncthreads();
    }
  }
  // ---- epilogue (C/D layout: col=lane&15, row=(lane>>4)*4+reg) ----
  #pragma unroll
  for (int fm = 0; fm < 2; ++fm) {
    const int rbase = m0 + w * 32 + fm * 16 + q * 4;
    #pragma unroll
    for (int rr = 0; rr < 4; ++rr) {
      const int row = rbase + rr;
      float bs = p.bias[row];
      float sBN = 1.f, tBN = 0.f;
      if (EPI == 2) {
        float sc = p.gamma[row] / sqrtf(p.var[row] + 1e-5f);
        sBN = sc; tBN = p.beta[row] - p.mean[row] * sc;
      }
      #pragma unroll
      for (int fn = 0; fn < 4; ++fn) {
        const int col = n0 + fn * 16 + lm;
        if (col < NX) {
          float v = acc[fm][fn][rr] + bs;
          if (EPI == 2) v = geluf(v * sBN + tBN);
          if (OUT16) {
            p.out16[((size_t)b * NX + col) * p.oC2p + p.oCoff + row] = (_Float16)v;
          } else {
            p.out[(size_t)b * (256 * NX) + (size_t)row * NX + col] = v;
          }
        }
      }
    }
  }
}

// ---------------- sparsemax (exact, Michelot projection) ----------------
__global__ __launch_bounds__(256) void sparsemax_k(float* __restrict__ S, int d) {
  const int row = blockIdx.x;
  float* s = S + (size_t)row * d;
  const int tid = threadIdx.x;
  const int wid = tid >> 6, lane = tid & 63;
  float v[3]; bool act[3];
  #pragma unroll
  for (int j = 0; j < 3; ++j) {
    int idx = tid + j * 256;
    bool ok = idx < d;
    v[j] = ok ? s[idx] : -1e30f;
    act[j] = ok;
  }
  __shared__ float red[16];
  float mx = fmaxf(fmaxf(v[0], v[1]), v[2]);
  #pragma unroll
  for (int o = 32; o; o >>= 1) mx = fmaxf(mx, __shfl_down(mx, o));
  if (lane == 0) red[wid] = mx;
  __syncthreads();
  if (tid == 0) red[0] = fmaxf(fmaxf(red[0], red[1]), fmaxf(red[2], red[3]));
  __syncthreads();
  mx = red[0];
  __syncthreads();
  #pragma unroll
  for (int j = 0; j < 3; ++j) if (act[j]) v[j] -= mx;
  float tau = 0.f;
  for (int it = 0; it < 700; ++it) {
    float ls = 0.f, lc = 0.f;
    #pragma unroll
    for (int j = 0; j < 3; ++j) if (act[j]) { ls += v[j]; lc += 1.f; }
    #pragma unroll
    for (int o = 32; o; o >>= 1) { ls += __shfl_down(ls, o); lc += __shfl_down(lc, o); }
    if (lane == 0) { red[wid] = ls; red[4 + wid] = lc; }
    __syncthreads();
    if (tid == 0) {
      float Sm = 0.f, Cn = 0.f;
      #pragma unroll
      for (int w2 = 0; w2 < 4; ++w2) { Sm += red[w2]; Cn += red[4 + w2]; }
      red[8] = (Sm - 1.f) / Cn;
      red[9] = 0.f;
    }
    __syncthreads();
    tau = red[8];
    bool ch = false;
    #pragma unroll
    for (int j = 0; j < 3; ++j)
      if (act[j] && v[j] <= tau) { act[j] = false; ch = true; }
    if (ch) red[9] = 1.f;
    __syncthreads();
    if (red[9] == 0.f) break;
  }
  #pragma unroll
  for (int j = 0; j < 3; ++j) {
    int idx = tid + j * 256;
    if (idx < d) s[idx] = fmaxf(v[j] - tau, 0.f);
  }
}

// ------------- mask: any(si2>0) -> largest 8-CC -> fill holes -------------
__global__ __launch_bounds__(640) void cc_kernel(const float* __restrict__ si2,
                                                 float* __restrict__ mask) {
  const int b = blockIdx.x, tid = threadIdx.x;
  __shared__ int lab[625];
  __shared__ int counts[626];
  __shared__ int flag, best;
  const bool in = tid < 625;
  const int y = tid / 25, x = tid - (tid / 25) * 25;
  bool mv = false;
  if (in) {
    const float* base = si2 + (size_t)b * NZ * NX + tid;
    for (int n = 0; n < NZ; ++n) mv = mv || (base[(size_t)n * NX] > 0.f);
    lab[tid] = mv ? tid + 1 : 0;
  }
  __syncthreads();
  for (int it = 0; it < 1000; ++it) {
    if (tid == 0) flag = 0;
    __syncthreads();
    int nl = 0;
    if (in && mv) {
      nl = lab[tid];
      #pragma unroll
      for (int dy = -1; dy <= 1; ++dy)
        #pragma unroll
        for (int dx = -1; dx <= 1; ++dx) {
          int yy = y + dy, xx = x + dx;
          if ((unsigned)yy < 25u && (unsigned)xx < 25u) nl = max(nl, lab[yy * 25 + xx]);
        }
    }
    __syncthreads();
    if (in && mv && nl != lab[tid]) { lab[tid] = nl; flag = 1; }
    __syncthreads();
    if (flag == 0) break;
  }
  if (tid < 626) counts[tid] = (tid == 0) ? -1 : 0;
  if (tid == 0) best = (int)0x80000000;
  __syncthreads();
  if (in && mv) atomicAdd(&counts[lab[tid]], 1);
  __syncthreads();
  if (tid < 626) atomicMax(&best, counts[tid] * 1024 + (1023 - tid));
  __syncthreads();
  const int largest = 1023 - (best & 1023);
  const bool comp = in && mv && (lab[tid] == largest);
  const bool bg = in && !comp;
  const bool border = in && (y == 0 || y == 24 || x == 0 || x == 24);
  __syncthreads();
  if (in) lab[tid] = (bg && border) ? 1 : 0;
  __syncthreads();
  for (int it = 0; it < 1000; ++it) {
    if (tid == 0) flag = 0;
    __syncthreads();
    int r = 0;
    if (in && bg && !lab[tid]) {
      if (y > 0  && lab[tid - 25]) r = 1;
      if (y < 24 && lab[tid + 25]) r = 1;
      if (x > 0  && lab[tid - 1])  r = 1;
      if (x < 24 && lab[tid + 1])  r = 1;
    }
    __syncthreads();
    if (r) { lab[tid] = 1; flag = 1; }
    __syncthreads();
    if (flag == 0) break;
  }
  if (in) mask[(size_t)b * NX + tid] = lab[tid] ? 0.f : 1.f;
}

extern "C" void kernel_launch(void* const* d_in, const int* in_sizes, int n_in,
                              void* d_out, int out_size, void* d_ws, size_t ws_size,
                              hipStream_t stream) {
  const float* zf     = (const float*)d_in[0];
  const float* xf     = (const float*)d_in[1];
  const float* sup_w  = (const float*)d_in[2];
  const float* sup_b  = (const float*)d_in[3];
  const float* sup_g  = (const float*)d_in[4];
  const float* sup_be = (const float*)d_in[5];
  const float* sup_m  = (const float*)d_in[6];
  const float* sup_v  = (const float*)d_in[7];
  const float* q_w    = (const float*)d_in[8];
  const float* q_b    = (const float*)d_in[9];
  const float* q_g    = (const float*)d_in[10];
  const float* q_be   = (const float*)d_in[11];
  const float* q_m    = (const float*)d_in[12];
  const float* q_v    = (const float*)d_in[13];
  const float* g_w1   = (const float*)d_in[14];
  const float* g_b1   = (const float*)d_in[15];
  const float* g_w2   = (const float*)d_in[16];
  const float* g_b2   = (const float*)d_in[17];
  const float* g_g    = (const float*)d_in[18];
  const float* g_be   = (const float*)d_in[19];
  const float* g_m    = (const float*)d_in[20];
  const float* g_v    = (const float*)d_in[21];
  const float* fi_w   = (const float*)d_in[22];
  const float* fi_b   = (const float*)d_in[23];
  const float* fi_g   = (const float*)d_in[24];
  const float* fi_be  = (const float*)d_in[25];
  const float* fi_m   = (const float*)d_in[26];
  const float* fi_v   = (const float*)d_in[27];
  const float* fi1_w  = (const float*)d_in[28];
  const float* fi1_b  = (const float*)d_in[29];
  const float* fi1_g  = (const float*)d_in[30];
  const float* fi1_be = (const float*)d_in[31];
  const float* fi1_m  = (const float*)d_in[32];
  const float* fi1_v  = (const float*)d_in[33];

  float* ws = (float*)d_ws;
  float* xf_trans = ws;                     // 5,120,000 (dead after step 9 -> reused for f16 weights)
  float* zf_trans = xf_trans + 5120000;     // 1,384,448
  float* zf_s     = zf_trans + 1384448;     // 913,952
  float* zp2      = zf_s + 913952;          // 1,384,448
  float* si       = zp2 + 1384448;          // 3,380,000
  float* si2      = si + 3380000;           // 3,380,000
  float* maskb    = si2 + 3380000;          // 20,000
  float* tail     = maskb + 20000;

  // f16 activation buffers (fresh space)
  _Float16* xf16 = (_Float16*)tail;         // 32*625*256 = 5,120,000 f16
  _Float16* gt16 = xf16 + 5120000;          // 32*625*256
  _Float16* Ucat = gt16 + 5120000;          // 32*625*512 = 10,240,000
  _Float16* S16  = Ucat + 10240000;         // 32*625*192 = 3,840,000

  // f16 weight buffers overlay the (dead) xf_trans region
  _Float16* wt_g1  = (_Float16*)xf_trans;   // 9*256*256   = 589,824
  _Float16* wt_g2  = wt_g1 + 589824;        // 1*256*256   = 65,536
  _Float16* wt_fi  = wt_g2 + 65536;         // 1*256*192   = 49,152
  _Float16* wt_fi1 = wt_fi + 49152;         // 25*256*512  = 3,276,800  (total 1.99M f32 < 5.12M)

  dim3 blk(256);
  GP p;

  // ---- mask-decision chain (exact fp32) ----
  // 1) xf_trans = gelu(bn_q(q_w @ xf + q_b))
  p = GP{}; p.A = q_w; p.B = xf; p.bias = q_b;
  p.gamma = q_g; p.beta = q_be; p.mean = q_m; p.var = q_v;
  p.out = xf_trans; p.M = CC; p.N = NX; p.K = CC;
  p.aB = 0; p.bB = (long)CC * NX; p.outB = (long)CC * NX;
  gemm_k<0,2><<<dim3(10,4,BB), blk, 0, stream>>>(p);

  // 2) zf_trans = gelu(bn_sup(sup_w @ zf + sup_b))
  p = GP{}; p.A = sup_w; p.B = zf; p.bias = sup_b;
  p.gamma = sup_g; p.beta = sup_be; p.mean = sup_m; p.var = sup_v;
  p.out = zf_trans; p.M = CC; p.N = NZ; p.K = CC;
  p.aB = 0; p.bB = (long)CC * NZ; p.outB = (long)CC * NZ;
  gemm_k<0,2><<<dim3(3,4,BB), blk, 0, stream>>>(p);

  // 5) zf_s_logits[n,m] = sum_c zf_trans[c,n] * zf_trans[c,m]
  p = GP{}; p.A = zf_trans; p.B = zf_trans;
  p.out = zf_s; p.M = NZ; p.N = NZ; p.K = CC;
  p.aB = (long)CC * NZ; p.bB = (long)CC * NZ; p.outB = (long)NZ * NZ;
  gemm_k<1,0><<<dim3(3,3,BB), blk, 0, stream>>>(p);

  // 6) zf_s = sparsemax(zf_s_logits)
  sparsemax_k<<<BB * NZ, blk, 0, stream>>>(zf_s, NZ);

  // 7) zp2[c,m] = zf[c,m] + sum_n zf[c,n] * zf_s[n,m]
  p = GP{}; p.A = zf; p.B = zf_s; p.resid = zf;
  p.out = zp2; p.M = CC; p.N = NZ; p.K = NZ;
  p.aB = (long)CC * NZ; p.bB = (long)NZ * NZ; p.outB = (long)CC * NZ;
  gemm_k<0,3><<<dim3(3,4,BB), blk, 0, stream>>>(p);

  // 8) si_logits[n,m] = sum_c zp2[c,n] * xf[c,m]
  p = GP{}; p.A = zp2; p.B = xf;
  p.out = si; p.M = NZ; p.N = NX; p.K = CC;
  p.aB = (long)CC * NZ; p.bB = (long)CC * NX; p.outB = (long)NZ * NX;
  gemm_k<1,0><<<dim3(10,3,BB), blk, 0, stream>>>(p);

  // 9) si2_logits[n,m] = sum_c zp2[c,n] * xf_trans[c,m]
  p = GP{}; p.A = zp2; p.B = xf_trans;
  p.out = si2; p.M = NZ; p.N = NX; p.K = CC;
  p.aB = (long)CC * NZ; p.bB = (long)CC * NX; p.outB = (long)NZ * NX;
  gemm_k<1,0><<<dim3(10,3,BB), blk, 0, stream>>>(p);

  // 10) sparsemax rows of length 625
  sparsemax_k<<<BB * NZ, blk, 0, stream>>>(si, NX);
  sparsemax_k<<<BB * NZ, blk, 0, stream>>>(si2, NX);

  // 11) mask from si2
  cc_kernel<<<BB, dim3(640), 0, stream>>>(si2, maskb);

  // ---- xf_trans now dead: build f16 weights in its space ----
  wtr_k<<<(9*256*256 + 255)/256,  blk, 0, stream>>>(g_w1,  wt_g1,  256, 256, 256, 9);
  wtr_k<<<(256*256   + 255)/256,  blk, 0, stream>>>(g_w2,  wt_g2,  256, 256, 256, 1);
  wtr_k<<<(256*192   + 255)/256,  blk, 0, stream>>>(fi_w,  wt_fi,  256, 169, 192, 1);
  wtr_k<<<(25*256*512+ 255)/256,  blk, 0, stream>>>(fi1_w, wt_fi1, 256, 512, 512, 25);

  // ---- activation conversions to f16 NHWC ----
  cvt_k<<<(long)(BB*NX*256 + 255)/256, blk, 0, stream>>>(xf, nullptr, xf16, 256, 256, (long)BB*NX*256);
  cvt_k<<<(long)(BB*NX*192 + 255)/256, blk, 0, stream>>>(si, si2, S16, 169, 192, (long)BB*NX*192);

  // ---- output path on MFMA (f16 in, fp32 accum), NHWC B operands ----
  MP mp;

  // 3) gt16 = conv3x3(xf, g_w1) + g_b1   (f16 NHWC out)
  mp = MP{}; mp.Wt = wt_g1; mp.U = xf16; mp.bias = g_b1;
  mp.out16 = gt16; mp.R = 9; mp.Rw = 3; mp.C2p = 256;
  mp.uB = (long)NX * 256; mp.oC2p = 256; mp.oCoff = 0;
  mgemm_k<1,1,0><<<dim3(10,2,BB), blk, 0, stream>>>(mp);

  // 4) Ucat[:,256:512] = gelu(bn_g(g_w2 @ gt16 + g_b2))
  mp = MP{}; mp.Wt = wt_g2; mp.U = gt16; mp.bias = g_b2;
  mp.gamma = g_g; mp.beta = g_be; mp.mean = g_m; mp.var = g_v;
  mp.out16 = Ucat; mp.R = 1; mp.Rw = 1; mp.C2p = 256;
  mp.uB = (long)NX * 256; mp.oC2p = 512; mp.oCoff = 256;
  mgemm_k<2,1,0><<<dim3(10,2,BB), blk, 0, stream>>>(mp);

  // 12) Ucat[:,0:256] = gelu(bn_fi(fi_w @ (si + si2) + fi_b))
  mp = MP{}; mp.Wt = wt_fi; mp.U = S16; mp.bias = fi_b;
  mp.gamma = fi_g; mp.beta = fi_be; mp.mean = fi_m; mp.var = fi_v;
  mp.out16 = Ucat; mp.R = 1; mp.Rw = 1; mp.C2p = 192;
  mp.uB = (long)NX * 192; mp.oC2p = 512; mp.oCoff = 0;
  mgemm_k<2,1,0><<<dim3(10,2,BB), blk, 0, stream>>>(mp);

  // 13) out = gelu(bn_fi1(conv5x5(Ucat with mask on c>=256, fi1_w) + fi1_b))
  mp = MP{}; mp.Wt = wt_fi1; mp.U = Ucat; mp.mask = maskb;
  mp.bias = fi1_b; mp.gamma = fi1_g; mp.beta = fi1_be; mp.mean = fi1_m; mp.var = fi1_v;
  mp.out = (float*)d_out; mp.R = 25; mp.Rw = 5; mp.C2p = 512;
  mp.uB = (long)NX * 512;
  mgemm_k<2,0,1><<<dim3(10,2,BB), blk, 0, stream>>>(mp);
}